// Round 14
// baseline (2225.264 us; speedup 1.0000x reference)
//
#include <hip/hip_runtime.h>
#include <math.h>

#define VOCAB 50257
#define HID   1024
#define G4    4096
#define LZD   128
#define CDD   32
#define SEQ   256
#define NWG   256          // scan WGs: WG q owns h-units 4q..4q+3
#define DECTAG 300u        // decoder tag base (disjoint from encoder tags 1..256)

typedef unsigned long long ull;

// ---------------- helpers ----------------
__device__ __forceinline__ float sigm(float x){ return 1.0f/(1.0f+expf(-x)); }

// tagged-word protocol: 64-bit relaxed agent atomic = (tag<<32)|float_bits.
__device__ __forceinline__ void pub_val(ull* p, float x, unsigned tag){
  ull v = ((ull)tag<<32) | (ull)__float_as_uint(x);
  __hip_atomic_store(p, v, __ATOMIC_RELAXED, __HIP_MEMORY_SCOPE_AGENT);
}
__device__ __forceinline__ ull ald(ull* p){
  return __hip_atomic_load(p, __ATOMIC_RELAXED, __HIP_MEMORY_SCOPE_AGENT);
}
__device__ __forceinline__ float poll_val(ull* p, unsigned tag){
  ull v = ald(p);
  while((unsigned)(v>>32) != tag){ __builtin_amdgcn_s_sleep(1); v = ald(p); }
  return __uint_as_float((unsigned)v);
}
// all-thread poll of 4 strided words; ALL stale words re-issued in parallel each
// iteration (1 LLC RTT per round, not up to 4 serial RTTs). [R13-verified −190µs]
__device__ __forceinline__ void poll4(ull* slot, float* hb, int tid, unsigned tag){
  ull *p0=&slot[tid], *p1=&slot[tid+256], *p2=&slot[tid+512], *p3=&slot[tid+768];
  ull v0=ald(p0), v1=ald(p1), v2=ald(p2), v3=ald(p3);
  for(;;){
    const bool o0=((unsigned)(v0>>32)==tag), o1=((unsigned)(v1>>32)==tag);
    const bool o2=((unsigned)(v2>>32)==tag), o3=((unsigned)(v3>>32)==tag);
    if(o0 & o1 & o2 & o3) break;
    __builtin_amdgcn_s_sleep(1);
    if(!o0) v0=ald(p0);
    if(!o1) v1=ald(p1);
    if(!o2) v2=ald(p2);
    if(!o3) v3=ald(p3);
  }
  hb[tid]     = __uint_as_float((unsigned)v0);
  hb[tid+256] = __uint_as_float((unsigned)v1);
  hb[tid+512] = __uint_as_float((unsigned)v2);
  hb[tid+768] = __uint_as_float((unsigned)v3);
}

// JAX uniform bits -> sqrt(2)*erfinv (Giles poly, == XLA f32 ErfInv)
__device__ __forceinline__ float eps_from_bits(unsigned bits){
  float f = __uint_as_float((bits>>9) | 0x3F800000u) - 1.0f;
  const float MINV = -0.99999994f;
  float u = fmaxf(MINV, f*2.0f + MINV);
  float w = -log1pf(-u*u);
  float p;
  if(w < 5.0f){
    w -= 2.5f;
    p =  2.81022636e-08f;
    p = fmaf(p,w, 3.43273939e-07f);
    p = fmaf(p,w,-3.5233877e-06f);
    p = fmaf(p,w,-4.39150654e-06f);
    p = fmaf(p,w, 0.00021858087f);
    p = fmaf(p,w,-0.00125372503f);
    p = fmaf(p,w,-0.00417768164f);
    p = fmaf(p,w, 0.246640727f);
    p = fmaf(p,w, 1.50140941f);
  }else{
    w = sqrtf(w) - 3.0f;
    p = -0.000200214257f;
    p = fmaf(p,w, 0.000100950558f);
    p = fmaf(p,w, 0.00134934322f);
    p = fmaf(p,w,-0.00367342844f);
    p = fmaf(p,w, 0.00573950773f);
    p = fmaf(p,w,-0.0076224613f);
    p = fmaf(p,w, 0.00943887047f);
    p = fmaf(p,w, 1.00167406f);
    p = fmaf(p,w, 2.83297682f);
  }
  return 1.4142135623730951f * (p*u);
}

// ---------------- prep: gathers + tag reset ----------------
__global__ __launch_bounds__(256) void vae_embed(
    const int* __restrict__ tok, const float* __restrict__ enc_emb,
    const float* __restrict__ dec_emb,
    float* __restrict__ xenc, float* __restrict__ xdec, ull* __restrict__ tags)
{
  const int b = blockIdx.x, tid = threadIdx.x;
  if(b == SEQ){
    for(int i=tid; i<2*HID+2*LZD+LZD+CDD; i+=256)
      __hip_atomic_store(&tags[i], 0ULL, __ATOMIC_RELAXED, __HIP_MEMORY_SCOPE_AGENT);
    return;
  }
  const int te = tok[b];
  const int td = (b==0) ? 0 : tok[b-1];                   // SOS = 0
  float4 v = *(const float4*)(enc_emb + (size_t)te*HID + tid*4);
  *(float4*)(xenc + (size_t)b*HID + tid*4) = v;
  float4 u = *(const float4*)(dec_emb + (size_t)td*HID + tid*4);
  u.x=fmaxf(u.x,0.f); u.y=fmaxf(u.y,0.f); u.z=fmaxf(u.z,0.f); u.w=fmaxf(u.w,0.f);
  *(float4*)(xdec + (size_t)b*HID + tid*4) = u;
}

// ---------------- merged pre-GEMM: z=0 enc, z=1 dec. C[M,G4] = X @ Wih^T + bih + bhh ----
__global__ __launch_bounds__(256) void gemm_pre(
    const float* __restrict__ xe, const float* __restrict__ Wihe,
    const float* __restrict__ be1, const float* __restrict__ be2,
    const float* __restrict__ xd, const float* __restrict__ Wihd,
    const float* __restrict__ bd1, const float* __restrict__ bd2,
    float* __restrict__ preE, float* __restrict__ preD)
{
  const int z = blockIdx.z;
  const float* A  = z ? xd   : xe;
  const float* B  = z ? Wihd : Wihe;
  const float* b1 = z ? bd1  : be1;
  const float* b2 = z ? bd2  : be2;
  float* C        = z ? preD : preE;
  const int K = HID, N = G4;

  __shared__ float As[16*68];
  __shared__ float Bs[16*68];
  const int tid = threadIdx.x;
  const int bn = blockIdx.x<<6, bm = blockIdx.y<<6;
  const int lr = tid>>2, lc4 = (tid&3)<<2;
  const int tx = tid&15, ty = tid>>4;
  const float* Arow = A + (size_t)(bm+lr)*K + lc4;
  const float* Brow = B + (size_t)(bn+lr)*K + lc4;
  float acc[4][4] = {};
  for(int kt=0; kt<K; kt+=16){
    float4 av = *(const float4*)(Arow + kt);
    float4 bv = *(const float4*)(Brow + kt);
    __syncthreads();
    As[(lc4+0)*68+lr]=av.x; As[(lc4+1)*68+lr]=av.y; As[(lc4+2)*68+lr]=av.z; As[(lc4+3)*68+lr]=av.w;
    Bs[(lc4+0)*68+lr]=bv.x; Bs[(lc4+1)*68+lr]=bv.y; Bs[(lc4+2)*68+lr]=bv.z; Bs[(lc4+3)*68+lr]=bv.w;
    __syncthreads();
#pragma unroll
    for(int k=0;k<16;++k){
      float4 a = *(const float4*)(As + k*68 + (ty<<2));
      float4 b = *(const float4*)(Bs + k*68 + (tx<<2));
      float a4[4] = {a.x,a.y,a.z,a.w};
      float b4[4] = {b.x,b.y,b.z,b.w};
#pragma unroll
      for(int i=0;i<4;++i)
#pragma unroll
        for(int j=0;j<4;++j)
          acc[i][j] = fmaf(a4[i], b4[j], acc[i][j]);
    }
  }
  const int n0 = bn + (tx<<2);
#pragma unroll
  for(int i=0;i<4;++i){
    const int m = bm + (ty<<2) + i;
#pragma unroll
    for(int j=0;j<4;++j){
      const int n = n0+j;
      C[(size_t)m*N + n] = acc[i][j] + b1[n] + b2[n];
    }
  }
}

// ---------------- fp32 GEMM 128x128 tile, BK=16, LDS double-buffer, 1 barrier/K-step ----------------
__global__ __launch_bounds__(256) void gemm_nt_128(
    const float* __restrict__ A, const float* __restrict__ B,
    const float* __restrict__ bias, float* __restrict__ C, int K, int N)
{
  __shared__ float As[2][16][132];
  __shared__ float Bs[2][16][132];
  const int tid = threadIdx.x;
  const int bn = blockIdx.x<<7, bm = blockIdx.y<<7;
  const int tx = tid&15, ty = tid>>4;
  const int lr = tid>>1, lc = (tid&1)<<3;     // row 0..127, col-offset 0/8
  const float* Arow = A + (size_t)(bm+lr)*K + lc;
  const float* Brow = B + (size_t)(bn+lr)*K + lc;
  const bool bval = (bn+lr) < N;

  float4 a0v = *(const float4*)(Arow);
  float4 a1v = *(const float4*)(Arow + 4);
  float4 b0v = bval ? *(const float4*)(Brow)     : make_float4(0,0,0,0);
  float4 b1v = bval ? *(const float4*)(Brow + 4) : make_float4(0,0,0,0);
  // stage 0
  As[0][lc+0][lr]=a0v.x; As[0][lc+1][lr]=a0v.y; As[0][lc+2][lr]=a0v.z; As[0][lc+3][lr]=a0v.w;
  As[0][lc+4][lr]=a1v.x; As[0][lc+5][lr]=a1v.y; As[0][lc+6][lr]=a1v.z; As[0][lc+7][lr]=a1v.w;
  Bs[0][lc+0][lr]=b0v.x; Bs[0][lc+1][lr]=b0v.y; Bs[0][lc+2][lr]=b0v.z; Bs[0][lc+3][lr]=b0v.w;
  Bs[0][lc+4][lr]=b1v.x; Bs[0][lc+5][lr]=b1v.y; Bs[0][lc+6][lr]=b1v.z; Bs[0][lc+7][lr]=b1v.w;
  __syncthreads();

  float acc[8][8] = {};
  int cur = 0;
  for(int kt=0; kt<K; kt+=16){
    const bool more = (kt+16 < K);
    if(more){
      a0v = *(const float4*)(Arow + kt + 16);
      a1v = *(const float4*)(Arow + kt + 20);
      b0v = bval ? *(const float4*)(Brow + kt + 16) : make_float4(0,0,0,0);
      b1v = bval ? *(const float4*)(Brow + kt + 20) : make_float4(0,0,0,0);
    }
#pragma unroll
    for(int k=0;k<16;++k){
      float a8[8], b8[8];
      *(float4*)(a8)   = *(const float4*)(&As[cur][k][ty*8]);
      *(float4*)(a8+4) = *(const float4*)(&As[cur][k][ty*8+4]);
      *(float4*)(b8)   = *(const float4*)(&Bs[cur][k][tx*8]);
      *(float4*)(b8+4) = *(const float4*)(&Bs[cur][k][tx*8+4]);
#pragma unroll
      for(int i=0;i<8;++i)
#pragma unroll
        for(int j=0;j<8;++j)
          acc[i][j] = fmaf(a8[i], b8[j], acc[i][j]);
    }
    if(more){
      const int nx = cur^1;
      As[nx][lc+0][lr]=a0v.x; As[nx][lc+1][lr]=a0v.y; As[nx][lc+2][lr]=a0v.z; As[nx][lc+3][lr]=a0v.w;
      As[nx][lc+4][lr]=a1v.x; As[nx][lc+5][lr]=a1v.y; As[nx][lc+6][lr]=a1v.z; As[nx][lc+7][lr]=a1v.w;
      Bs[nx][lc+0][lr]=b0v.x; Bs[nx][lc+1][lr]=b0v.y; Bs[nx][lc+2][lr]=b0v.z; Bs[nx][lc+3][lr]=b0v.w;
      Bs[nx][lc+4][lr]=b1v.x; Bs[nx][lc+5][lr]=b1v.y; Bs[nx][lc+6][lr]=b1v.z; Bs[nx][lc+7][lr]=b1v.w;
    }
    __syncthreads();
    cur ^= 1;
  }

  const int m0 = bm + ty*8, n0 = bn + tx*8;
#pragma unroll
  for(int i=0;i<8;++i){
#pragma unroll
    for(int j=0;j<8;++j){
      const int n = n0+j;
      if(n < N) C[(size_t)(m0+i)*N + n] = acc[i][j] + bias[n];
    }
  }
}

// ---------------- persistent scan: R13 champion (UNCHANGED — control) ----------------
__global__ __launch_bounds__(256,1) void vae_scan(
    const float* __restrict__ enc_Whh, const float* __restrict__ dec_Whh,
    const float* __restrict__ pre_enc, const float* __restrict__ pre_dec,
    const float* __restrict__ h0in, const float* __restrict__ c0in,
    const float* __restrict__ ccond,
    const float* __restrict__ mean_W, const float* __restrict__ mean_b,
    const float* __restrict__ logvar_W, const float* __restrict__ logvar_b,
    const float* __restrict__ lc_W, const float* __restrict__ lc_b,
    ull* __restrict__ h_tag, ull* __restrict__ mlv_tag, ull* __restrict__ lat_tag,
    float* __restrict__ Hdec, float* __restrict__ out_mean, float* __restrict__ out_logvar)
{
  __shared__ float W_lds[16*1024];   // 64 KB, current phase
  __shared__ float h_lds[HID];
  __shared__ float lat_lds[LZD+CDD];
  __shared__ float sh_mlv[2*LZD];
  __shared__ float gbuf[16];
  __shared__ float redb[4];

  const int q = blockIdx.x, tid = threadIdx.x;
  const int g = tid>>4, l = tid&15;     // 16 groups x 16 lanes
  const int gate = g&3, ul = g>>2;
  const int u4 = 4*q;

  // ---- load encoder W_hh slice (conflict-free 16-lane-row layout) ----
  for(int r=0;r<16;++r){
    const float* src = enc_Whh + ((size_t)((r&3)*HID + u4 + (r>>2)))*HID;
    *(float4*)(&W_lds[r*1024 + tid*4]) = *(const float4*)(src + tid*4);
  }
  float creg = (tid<4) ? c0in[u4+tid] : 0.0f;

  // ---- encoder scan (2 barriers/step) ----
  for(int t=0; t<SEQ; ++t){
    float pv = 0.f;
    if(l==0) pv = pre_enc[(size_t)t*G4 + gate*HID + u4 + ul];  // issue-early
    if(t==0){
#pragma unroll
      for(int j=0;j<4;++j) h_lds[tid+j*256] = h0in[tid+j*256];
    }else{
      poll4(h_tag + (t&1)*HID, h_lds, tid, (unsigned)t);
    }
    __syncthreads();                                  // B1
    float a0=0,a1=0,a2=0,a3=0;
    {
      const float* wr = &W_lds[g*1024 + l*4];
      const float* hr = &h_lds[l*4];
#pragma unroll
      for(int kk=0; kk<16; ++kk){
        float4 wv = *(const float4*)(wr + kk*64);
        float4 hv = *(const float4*)(hr + kk*64);
        a0 = fmaf(wv.x, hv.x, a0);
        a1 = fmaf(wv.y, hv.y, a1);
        a2 = fmaf(wv.z, hv.z, a2);
        a3 = fmaf(wv.w, hv.w, a3);
      }
    }
    float s = (a0+a1)+(a2+a3);
    s += __shfl_xor(s,1); s += __shfl_xor(s,2); s += __shfl_xor(s,4); s += __shfl_xor(s,8);
    if(l==0) gbuf[g] = s + pv;
    __syncthreads();                                  // B2
    if(tid<4){
      float gi=gbuf[tid*4+0], gf=gbuf[tid*4+1], gg=gbuf[tid*4+2], go=gbuf[tid*4+3];
      float cn = sigm(gf)*creg + sigm(gi)*tanhf(gg);
      float hn = sigm(go)*tanhf(cn);
      creg = cn;
      pub_val(&h_tag[((t+1)&1)*HID + u4+tid], hn, (unsigned)(t+1));  // 1 coalesced 32B store
    }
  }

  // ---- mean/logvar: WG q computes row q of [mean;logvar]; h_enc = slot0 tag 256 ----
  {
    poll4(h_tag, h_lds, tid, (unsigned)SEQ);
    __syncthreads();
    const float* Wrow = (q < LZD) ? (mean_W + (size_t)q*HID)
                                  : (logvar_W + (size_t)(q-LZD)*HID);
    const float bias = (q < LZD) ? mean_b[q] : logvar_b[q-LZD];
    float4 hv = *(const float4*)(h_lds + tid*4);
    float4 wv = *(const float4*)(Wrow + tid*4);
    float p = hv.x*wv.x + hv.y*wv.y + hv.z*wv.z + hv.w*wv.w;
    p += __shfl_xor(p,1); p += __shfl_xor(p,2); p += __shfl_xor(p,4);
    p += __shfl_xor(p,8); p += __shfl_xor(p,16); p += __shfl_xor(p,32);
    if((tid&63)==0) redb[tid>>6] = p;
    __syncthreads();
    if(tid==0){
      float s = redb[0]+redb[1]+redb[2]+redb[3] + bias;
      pub_val(&mlv_tag[q], s, 1u);
      if(q < LZD) out_mean[q] = s; else out_logvar[q-LZD] = s;
    }
  }

  // ---- WG0: partitionable-threefry eps + latent ----
  if(q==0){
    sh_mlv[tid] = poll_val(&mlv_tag[tid], 1u);
    __syncthreads();
    if(tid < LZD){
      unsigned x0 = 0u, x1 = (unsigned)tid;          // counter (0, i)
      const unsigned ks[3] = {0u, 1u, 0x1BD11BDAu ^ 0u ^ 1u};  // key(1)
      x0 += ks[0]; x1 += ks[1];
      const int RA[4] = {13,15,26,6}, RB[4] = {17,29,16,24};
#pragma unroll
      for(int gg2=0; gg2<5; ++gg2){
        const int* R = (gg2&1) ? RB : RA;
#pragma unroll
        for(int qq=0;qq<4;++qq){
          x0 += x1;
          x1 = (x1 << R[qq]) | (x1 >> (32-R[qq]));
          x1 ^= x0;
        }
        x0 += ks[(gg2+1)%3];
        x1 += ks[(gg2+2)%3] + (unsigned)(gg2+1);
      }
      float e = eps_from_bits(x0 ^ x1);
      pub_val(&lat_tag[tid], fmaf(e, expf(0.5f*sh_mlv[LZD+tid]), sh_mlv[tid]), 1u);
    } else if(tid < LZD+CDD){
      pub_val(&lat_tag[tid], ccond[tid-LZD], 1u);
    }
  }

  // ---- switch to decoder weights; poll latent; dec h0 (tid<4 serial dot) ----
  for(int r=0;r<16;++r){
    const float* src = dec_Whh + ((size_t)((r&3)*HID + u4 + (r>>2)))*HID;
    *(float4*)(&W_lds[r*1024 + tid*4]) = *(const float4*)(src + tid*4);
  }
  if(tid < LZD+CDD) lat_lds[tid] = poll_val(&lat_tag[tid], 1u);
  __syncthreads();
  if(tid<4){
    const int j = u4 + tid;
    float s = lc_b[j];
    const float* wr = lc_W + (size_t)j*(LZD+CDD);
#pragma unroll 8
    for(int k=0;k<LZD+CDD;++k) s = fmaf(lat_lds[k], wr[k], s);
    creg = 0.0f;
    pub_val(&h_tag[j], s, DECTAG);   // slot 0, coalesced
  }

  // ---- decoder scan ----
  for(int t=0; t<SEQ; ++t){
    float pv = 0.f;
    if(l==0) pv = pre_dec[(size_t)t*G4 + gate*HID + u4 + ul];
    poll4(h_tag + (t&1)*HID, h_lds, tid, DECTAG + (unsigned)t);
    __syncthreads();                                  // B1
    float a0=0,a1=0,a2=0,a3=0;
    {
      const float* wr = &W_lds[g*1024 + l*4];
      const float* hr = &h_lds[l*4];
#pragma unroll
      for(int kk=0; kk<16; ++kk){
        float4 wv = *(const float4*)(wr + kk*64);
        float4 hv = *(const float4*)(hr + kk*64);
        a0 = fmaf(wv.x, hv.x, a0);
        a1 = fmaf(wv.y, hv.y, a1);
        a2 = fmaf(wv.z, hv.z, a2);
        a3 = fmaf(wv.w, hv.w, a3);
      }
    }
    float s = (a0+a1)+(a2+a3);
    s += __shfl_xor(s,1); s += __shfl_xor(s,2); s += __shfl_xor(s,4); s += __shfl_xor(s,8);
    if(l==0) gbuf[g] = s + pv;
    __syncthreads();                                  // B2
    if(tid<4){
      float gi=gbuf[tid*4+0], gf=gbuf[tid*4+1], gg=gbuf[tid*4+2], go=gbuf[tid*4+3];
      float cn = sigm(gf)*creg + sigm(gi)*tanhf(gg);
      float hn = sigm(go)*tanhf(cn);
      creg = cn;
      Hdec[(size_t)t*HID + u4 + tid] = hn;
      pub_val(&h_tag[((t+1)&1)*HID + u4+tid], hn, DECTAG + (unsigned)(t+1));
    }
  }
}

// ---------------- in-place log_softmax + first-index argmax ----------------
__global__ __launch_bounds__(256) void softmax_argmax(float* __restrict__ dist,
                                                      float* __restrict__ outTok)
{
  __shared__ float wm[4]; __shared__ int wi[4];
  __shared__ float s_max; __shared__ int s_idx; __shared__ float s_lz;
  const int t = blockIdx.x, tid = threadIdx.x;
  float* row = dist + (size_t)t*VOCAB;
  float m = -INFINITY; int idx = VOCAB;
  for(int i=tid; i<VOCAB; i+=256){
    float v = row[i];
    if(v > m){ m = v; idx = i; }
  }
  for(int d=1; d<64; d<<=1){
    float m2 = __shfl_xor(m, d); int i2 = __shfl_xor(idx, d);
    if(m2 > m || (m2 == m && i2 < idx)){ m = m2; idx = i2; }
  }
  if((tid&63)==0){ wm[tid>>6]=m; wi[tid>>6]=idx; }
  __syncthreads();
  if(tid==0){
    float mm = wm[0]; int ii = wi[0];
    for(int q=1;q<4;++q) if(wm[q]>mm || (wm[q]==mm && wi[q]<ii)){ mm=wm[q]; ii=wi[q]; }
    s_max = mm; s_idx = ii;
  }
  __syncthreads();
  const float M = s_max;
  float s = 0.f;
  for(int i=tid; i<VOCAB; i+=256) s += expf(row[i] - M);
  for(int d=1; d<64; d<<=1) s += __shfl_xor(s, d);
  if((tid&63)==0) wm[tid>>6] = s;
  __syncthreads();
  if(tid==0) s_lz = M + logf(wm[0]+wm[1]+wm[2]+wm[3]);
  __syncthreads();
  const float lz = s_lz;
  for(int i=tid; i<VOCAB; i+=256) row[i] -= lz;
  if(tid==0) outTok[t] = (float)s_idx;
}

// ---------------- launch ----------------
extern "C" void kernel_launch(void* const* d_in, const int* in_sizes, int n_in,
                              void* d_out, int out_size, void* d_ws, size_t ws_size,
                              hipStream_t stream)
{
  (void)in_sizes; (void)n_in; (void)out_size; (void)ws_size;
  const int*   tok      = (const int*)  d_in[0];
  const float* h0       = (const float*)d_in[1];
  const float* c0       = (const float*)d_in[2];
  const float* ccond    = (const float*)d_in[3];
  // d_in[4] = use_teacher_forcing (unused by reference body)
  const float* enc_emb  = (const float*)d_in[5];
  const float* enc_Wih  = (const float*)d_in[6];
  const float* enc_Whh  = (const float*)d_in[7];
  const float* enc_bih  = (const float*)d_in[8];
  const float* enc_bhh  = (const float*)d_in[9];
  const float* dec_emb  = (const float*)d_in[10];
  const float* dec_Wih  = (const float*)d_in[11];
  const float* dec_Whh  = (const float*)d_in[12];
  const float* dec_bih  = (const float*)d_in[13];
  const float* dec_bhh  = (const float*)d_in[14];
  const float* out_W    = (const float*)d_in[15];
  const float* out_b    = (const float*)d_in[16];
  const float* mean_W   = (const float*)d_in[17];
  const float* mean_b   = (const float*)d_in[18];
  const float* logvar_W = (const float*)d_in[19];
  const float* logvar_b = (const float*)d_in[20];
  const float* lc_W     = (const float*)d_in[21];
  const float* lc_b     = (const float*)d_in[22];

  float* ws      = (float*)d_ws;
  float* xenc    = ws;                       // 256*1024
  float* xdec    = xenc + SEQ*HID;           // 256*1024
  float* pre_enc = xdec + SEQ*HID;           // 256*4096
  float* pre_dec = pre_enc + (size_t)SEQ*G4; // 256*4096
  float* Hdec    = pre_dec + (size_t)SEQ*G4; // 256*1024
  ull*   tags    = (ull*)(Hdec + (size_t)SEQ*HID);  // 8B-aligned
  ull*   h_tag   = tags;                     // [2*1024]
  ull*   mlv_tag = h_tag + 2*HID;            // [256]
  ull*   lat_tag = mlv_tag + 2*LZD;          // [160]
  // total ~11.6 MB of ws

  float* out      = (float*)d_out;
  float* outTok   = out;                          // [256] tokens (as f32)
  float* dist     = out + SEQ;                    // [256,50257] log-softmax
  float* out_mean = dist + (size_t)SEQ*VOCAB;     // [128]
  float* out_lv   = out_mean + LZD;               // [128]

  hipLaunchKernelGGL(vae_embed, dim3(SEQ+1), dim3(256), 0, stream,
                     tok, enc_emb, dec_emb, xenc, xdec, tags);
  hipLaunchKernelGGL(gemm_pre, dim3(G4/64, SEQ/64, 2), dim3(256), 0, stream,
                     xenc, enc_Wih, enc_bih, enc_bhh,
                     xdec, dec_Wih, dec_bih, dec_bhh, pre_enc, pre_dec);
  hipLaunchKernelGGL(vae_scan, dim3(NWG), dim3(256), 0, stream,
                     enc_Whh, dec_Whh, pre_enc, pre_dec, h0, c0, ccond,
                     mean_W, mean_b, logvar_W, logvar_b, lc_W, lc_b,
                     h_tag, mlv_tag, lat_tag, Hdec, out_mean, out_lv);
  hipLaunchKernelGGL(gemm_nt_128, dim3((VOCAB+127)/128, SEQ/128), dim3(256), 0, stream,
                     Hdec, out_W, out_b, dist, HID, VOCAB);
  hipLaunchKernelGGL(softmax_argmax, dim3(SEQ), dim3(256), 0, stream, dist, outTok);
}

// Round 15
// 1867.561 us; speedup vs baseline: 1.1915x; 1.1915x over previous
//
#include <hip/hip_runtime.h>
#include <math.h>

#define VOCAB 50257
#define HID   1024
#define G4    4096
#define LZD   128
#define CDD   32
#define SEQ   256
#define NWG   256          // scan WGs: WG q owns h-units 4q..4q+3
#define DECTAG 300u        // decoder tag base (disjoint from encoder tags 1..256)

typedef unsigned long long ull;

// ---------------- helpers ----------------
__device__ __forceinline__ float sigm(float x){ return 1.0f/(1.0f+expf(-x)); }

// tagged-word protocol: 64-bit relaxed agent atomic = (tag<<32)|float_bits.
__device__ __forceinline__ void pub_val(ull* p, float x, unsigned tag){
  ull v = ((ull)tag<<32) | (ull)__float_as_uint(x);
  __hip_atomic_store(p, v, __ATOMIC_RELAXED, __HIP_MEMORY_SCOPE_AGENT);
}
__device__ __forceinline__ ull ald(ull* p){
  return __hip_atomic_load(p, __ATOMIC_RELAXED, __HIP_MEMORY_SCOPE_AGENT);
}
__device__ __forceinline__ float poll_val(ull* p, unsigned tag){
  ull v = ald(p);
  while((unsigned)(v>>32) != tag){ __builtin_amdgcn_s_sleep(1); v = ald(p); }
  return __uint_as_float((unsigned)v);
}
// all-thread poll of 4 strided words; ALL stale words re-issued in parallel each
// iteration (1 LLC RTT per round, not up to 4 serial RTTs). [R13-verified −190µs]
__device__ __forceinline__ void poll4(ull* slot, float* hb, int tid, unsigned tag){
  ull *p0=&slot[tid], *p1=&slot[tid+256], *p2=&slot[tid+512], *p3=&slot[tid+768];
  ull v0=ald(p0), v1=ald(p1), v2=ald(p2), v3=ald(p3);
  for(;;){
    const bool o0=((unsigned)(v0>>32)==tag), o1=((unsigned)(v1>>32)==tag);
    const bool o2=((unsigned)(v2>>32)==tag), o3=((unsigned)(v3>>32)==tag);
    if(o0 & o1 & o2 & o3) break;
    __builtin_amdgcn_s_sleep(1);
    if(!o0) v0=ald(p0);
    if(!o1) v1=ald(p1);
    if(!o2) v2=ald(p2);
    if(!o3) v3=ald(p3);
  }
  hb[tid]     = __uint_as_float((unsigned)v0);
  hb[tid+256] = __uint_as_float((unsigned)v1);
  hb[tid+512] = __uint_as_float((unsigned)v2);
  hb[tid+768] = __uint_as_float((unsigned)v3);
}

// JAX uniform bits -> sqrt(2)*erfinv (Giles poly, == XLA f32 ErfInv)
__device__ __forceinline__ float eps_from_bits(unsigned bits){
  float f = __uint_as_float((bits>>9) | 0x3F800000u) - 1.0f;
  const float MINV = -0.99999994f;
  float u = fmaxf(MINV, f*2.0f + MINV);
  float w = -log1pf(-u*u);
  float p;
  if(w < 5.0f){
    w -= 2.5f;
    p =  2.81022636e-08f;
    p = fmaf(p,w, 3.43273939e-07f);
    p = fmaf(p,w,-3.5233877e-06f);
    p = fmaf(p,w,-4.39150654e-06f);
    p = fmaf(p,w, 0.00021858087f);
    p = fmaf(p,w,-0.00125372503f);
    p = fmaf(p,w,-0.00417768164f);
    p = fmaf(p,w, 0.246640727f);
    p = fmaf(p,w, 1.50140941f);
  }else{
    w = sqrtf(w) - 3.0f;
    p = -0.000200214257f;
    p = fmaf(p,w, 0.000100950558f);
    p = fmaf(p,w, 0.00134934322f);
    p = fmaf(p,w,-0.00367342844f);
    p = fmaf(p,w, 0.00573950773f);
    p = fmaf(p,w,-0.0076224613f);
    p = fmaf(p,w, 0.00943887047f);
    p = fmaf(p,w, 1.00167406f);
    p = fmaf(p,w, 2.83297682f);
  }
  return 1.4142135623730951f * (p*u);
}

// ---------------- prep: gathers + tag reset ----------------
__global__ __launch_bounds__(256) void vae_embed(
    const int* __restrict__ tok, const float* __restrict__ enc_emb,
    const float* __restrict__ dec_emb,
    float* __restrict__ xenc, float* __restrict__ xdec, ull* __restrict__ tags)
{
  const int b = blockIdx.x, tid = threadIdx.x;
  if(b == SEQ){
    for(int i=tid; i<2*HID+2*LZD+LZD+CDD; i+=256)
      __hip_atomic_store(&tags[i], 0ULL, __ATOMIC_RELAXED, __HIP_MEMORY_SCOPE_AGENT);
    return;
  }
  const int te = tok[b];
  const int td = (b==0) ? 0 : tok[b-1];                   // SOS = 0
  float4 v = *(const float4*)(enc_emb + (size_t)te*HID + tid*4);
  *(float4*)(xenc + (size_t)b*HID + tid*4) = v;
  float4 u = *(const float4*)(dec_emb + (size_t)td*HID + tid*4);
  u.x=fmaxf(u.x,0.f); u.y=fmaxf(u.y,0.f); u.z=fmaxf(u.z,0.f); u.w=fmaxf(u.w,0.f);
  *(float4*)(xdec + (size_t)b*HID + tid*4) = u;
}

// ---------------- merged pre-GEMM: z=0 enc, z=1 dec. C[M,G4] = X @ Wih^T + bih + bhh ----
__global__ __launch_bounds__(256) void gemm_pre(
    const float* __restrict__ xe, const float* __restrict__ Wihe,
    const float* __restrict__ be1, const float* __restrict__ be2,
    const float* __restrict__ xd, const float* __restrict__ Wihd,
    const float* __restrict__ bd1, const float* __restrict__ bd2,
    float* __restrict__ preE, float* __restrict__ preD)
{
  const int z = blockIdx.z;
  const float* A  = z ? xd   : xe;
  const float* B  = z ? Wihd : Wihe;
  const float* b1 = z ? bd1  : be1;
  const float* b2 = z ? bd2  : be2;
  float* C        = z ? preD : preE;
  const int K = HID, N = G4;

  __shared__ float As[16*68];
  __shared__ float Bs[16*68];
  const int tid = threadIdx.x;
  const int bn = blockIdx.x<<6, bm = blockIdx.y<<6;
  const int lr = tid>>2, lc4 = (tid&3)<<2;
  const int tx = tid&15, ty = tid>>4;
  const float* Arow = A + (size_t)(bm+lr)*K + lc4;
  const float* Brow = B + (size_t)(bn+lr)*K + lc4;
  float acc[4][4] = {};
  for(int kt=0; kt<K; kt+=16){
    float4 av = *(const float4*)(Arow + kt);
    float4 bv = *(const float4*)(Brow + kt);
    __syncthreads();
    As[(lc4+0)*68+lr]=av.x; As[(lc4+1)*68+lr]=av.y; As[(lc4+2)*68+lr]=av.z; As[(lc4+3)*68+lr]=av.w;
    Bs[(lc4+0)*68+lr]=bv.x; Bs[(lc4+1)*68+lr]=bv.y; Bs[(lc4+2)*68+lr]=bv.z; Bs[(lc4+3)*68+lr]=bv.w;
    __syncthreads();
#pragma unroll
    for(int k=0;k<16;++k){
      float4 a = *(const float4*)(As + k*68 + (ty<<2));
      float4 b = *(const float4*)(Bs + k*68 + (tx<<2));
      float a4[4] = {a.x,a.y,a.z,a.w};
      float b4[4] = {b.x,b.y,b.z,b.w};
#pragma unroll
      for(int i=0;i<4;++i)
#pragma unroll
        for(int j=0;j<4;++j)
          acc[i][j] = fmaf(a4[i], b4[j], acc[i][j]);
    }
  }
  const int n0 = bn + (tx<<2);
#pragma unroll
  for(int i=0;i<4;++i){
    const int m = bm + (ty<<2) + i;
#pragma unroll
    for(int j=0;j<4;++j){
      const int n = n0+j;
      C[(size_t)m*N + n] = acc[i][j] + b1[n] + b2[n];
    }
  }
}

// ---------------- fp32 GEMM 128x128 tile, 8x8/thread, reg prefetch (R13 champion) ----------------
__global__ __launch_bounds__(256) void gemm_nt_128(
    const float* __restrict__ A, const float* __restrict__ B,
    const float* __restrict__ bias, float* __restrict__ C, int K, int N)
{
  __shared__ float As[8][132];
  __shared__ float Bs[8][132];
  const int tid = threadIdx.x;
  const int bn = blockIdx.x<<7, bm = blockIdx.y<<7;
  const int tx = tid&15, ty = tid>>4;
  const int lr = tid>>1, lc = (tid&1)<<2;
  const float* Arow = A + (size_t)(bm+lr)*K + lc;
  const float* Brow = B + (size_t)(bn+lr)*K + lc;
  const bool bval = (bn+lr) < N;
  float4 av = *(const float4*)(Arow);
  float4 bv = bval ? *(const float4*)(Brow) : make_float4(0.f,0.f,0.f,0.f);
  float acc[8][8] = {};
  for(int kt=0; kt<K; kt+=8){
    __syncthreads();                 // previous iteration's compute finished
    As[lc+0][lr]=av.x; As[lc+1][lr]=av.y; As[lc+2][lr]=av.z; As[lc+3][lr]=av.w;
    Bs[lc+0][lr]=bv.x; Bs[lc+1][lr]=bv.y; Bs[lc+2][lr]=bv.z; Bs[lc+3][lr]=bv.w;
    __syncthreads();
    if(kt+8 < K){                    // prefetch next tile, overlapped with compute
      av = *(const float4*)(Arow + kt + 8);
      bv = bval ? *(const float4*)(Brow + kt + 8) : make_float4(0.f,0.f,0.f,0.f);
    }
#pragma unroll
    for(int k=0;k<8;++k){
      float a8[8], b8[8];
      *(float4*)(a8)   = *(const float4*)(&As[k][ty*8]);
      *(float4*)(a8+4) = *(const float4*)(&As[k][ty*8+4]);
      *(float4*)(b8)   = *(const float4*)(&Bs[k][tx*8]);
      *(float4*)(b8+4) = *(const float4*)(&Bs[k][tx*8+4]);
#pragma unroll
      for(int i=0;i<8;++i)
#pragma unroll
        for(int j=0;j<8;++j)
          acc[i][j] = fmaf(a8[i], b8[j], acc[i][j]);
    }
  }
  const int m0 = bm + ty*8, n0 = bn + tx*8;
#pragma unroll
  for(int i=0;i<8;++i){
#pragma unroll
    for(int j=0;j<8;++j){
      const int n = n0+j;
      if(n < N) C[(size_t)(m0+i)*N + n] = acc[i][j] + bias[n];
    }
  }
}

// ---------------- persistent scan: R13 champion (UNCHANGED) ----------------
__global__ __launch_bounds__(256,1) void vae_scan(
    const float* __restrict__ enc_Whh, const float* __restrict__ dec_Whh,
    const float* __restrict__ pre_enc, const float* __restrict__ pre_dec,
    const float* __restrict__ h0in, const float* __restrict__ c0in,
    const float* __restrict__ ccond,
    const float* __restrict__ mean_W, const float* __restrict__ mean_b,
    const float* __restrict__ logvar_W, const float* __restrict__ logvar_b,
    const float* __restrict__ lc_W, const float* __restrict__ lc_b,
    ull* __restrict__ h_tag, ull* __restrict__ mlv_tag, ull* __restrict__ lat_tag,
    float* __restrict__ Hdec, float* __restrict__ out_mean, float* __restrict__ out_logvar)
{
  __shared__ float W_lds[16*1024];   // 64 KB, current phase
  __shared__ float h_lds[HID];
  __shared__ float lat_lds[LZD+CDD];
  __shared__ float sh_mlv[2*LZD];
  __shared__ float gbuf[16];
  __shared__ float redb[4];

  const int q = blockIdx.x, tid = threadIdx.x;
  const int g = tid>>4, l = tid&15;     // 16 groups x 16 lanes
  const int gate = g&3, ul = g>>2;
  const int u4 = 4*q;

  // ---- load encoder W_hh slice (conflict-free 16-lane-row layout) ----
  for(int r=0;r<16;++r){
    const float* src = enc_Whh + ((size_t)((r&3)*HID + u4 + (r>>2)))*HID;
    *(float4*)(&W_lds[r*1024 + tid*4]) = *(const float4*)(src + tid*4);
  }
  float creg = (tid<4) ? c0in[u4+tid] : 0.0f;

  // ---- encoder scan (2 barriers/step) ----
  for(int t=0; t<SEQ; ++t){
    float pv = 0.f;
    if(l==0) pv = pre_enc[(size_t)t*G4 + gate*HID + u4 + ul];  // issue-early
    if(t==0){
#pragma unroll
      for(int j=0;j<4;++j) h_lds[tid+j*256] = h0in[tid+j*256];
    }else{
      poll4(h_tag + (t&1)*HID, h_lds, tid, (unsigned)t);
    }
    __syncthreads();                                  // B1
    float a0=0,a1=0,a2=0,a3=0;
    {
      const float* wr = &W_lds[g*1024 + l*4];
      const float* hr = &h_lds[l*4];
#pragma unroll
      for(int kk=0; kk<16; ++kk){
        float4 wv = *(const float4*)(wr + kk*64);
        float4 hv = *(const float4*)(hr + kk*64);
        a0 = fmaf(wv.x, hv.x, a0);
        a1 = fmaf(wv.y, hv.y, a1);
        a2 = fmaf(wv.z, hv.z, a2);
        a3 = fmaf(wv.w, hv.w, a3);
      }
    }
    float s = (a0+a1)+(a2+a3);
    s += __shfl_xor(s,1); s += __shfl_xor(s,2); s += __shfl_xor(s,4); s += __shfl_xor(s,8);
    if(l==0) gbuf[g] = s + pv;
    __syncthreads();                                  // B2
    if(tid<4){
      float gi=gbuf[tid*4+0], gf=gbuf[tid*4+1], gg=gbuf[tid*4+2], go=gbuf[tid*4+3];
      float cn = sigm(gf)*creg + sigm(gi)*tanhf(gg);
      float hn = sigm(go)*tanhf(cn);
      creg = cn;
      pub_val(&h_tag[((t+1)&1)*HID + u4+tid], hn, (unsigned)(t+1));  // 1 coalesced 32B store
    }
  }

  // ---- mean/logvar: WG q computes row q of [mean;logvar]; h_enc = slot0 tag 256 ----
  {
    poll4(h_tag, h_lds, tid, (unsigned)SEQ);
    __syncthreads();
    const float* Wrow = (q < LZD) ? (mean_W + (size_t)q*HID)
                                  : (logvar_W + (size_t)(q-LZD)*HID);
    const float bias = (q < LZD) ? mean_b[q] : logvar_b[q-LZD];
    float4 hv = *(const float4*)(h_lds + tid*4);
    float4 wv = *(const float4*)(Wrow + tid*4);
    float p = hv.x*wv.x + hv.y*wv.y + hv.z*wv.z + hv.w*wv.w;
    p += __shfl_xor(p,1); p += __shfl_xor(p,2); p += __shfl_xor(p,4);
    p += __shfl_xor(p,8); p += __shfl_xor(p,16); p += __shfl_xor(p,32);
    if((tid&63)==0) redb[tid>>6] = p;
    __syncthreads();
    if(tid==0){
      float s = redb[0]+redb[1]+redb[2]+redb[3] + bias;
      pub_val(&mlv_tag[q], s, 1u);
      if(q < LZD) out_mean[q] = s; else out_logvar[q-LZD] = s;
    }
  }

  // ---- WG0: partitionable-threefry eps + latent ----
  if(q==0){
    sh_mlv[tid] = poll_val(&mlv_tag[tid], 1u);
    __syncthreads();
    if(tid < LZD){
      unsigned x0 = 0u, x1 = (unsigned)tid;          // counter (0, i)
      const unsigned ks[3] = {0u, 1u, 0x1BD11BDAu ^ 0u ^ 1u};  // key(1)
      x0 += ks[0]; x1 += ks[1];
      const int RA[4] = {13,15,26,6}, RB[4] = {17,29,16,24};
#pragma unroll
      for(int gg2=0; gg2<5; ++gg2){
        const int* R = (gg2&1) ? RB : RA;
#pragma unroll
        for(int qq=0;qq<4;++qq){
          x0 += x1;
          x1 = (x1 << R[qq]) | (x1 >> (32-R[qq]));
          x1 ^= x0;
        }
        x0 += ks[(gg2+1)%3];
        x1 += ks[(gg2+2)%3] + (unsigned)(gg2+1);
      }
      float e = eps_from_bits(x0 ^ x1);
      pub_val(&lat_tag[tid], fmaf(e, expf(0.5f*sh_mlv[LZD+tid]), sh_mlv[tid]), 1u);
    } else if(tid < LZD+CDD){
      pub_val(&lat_tag[tid], ccond[tid-LZD], 1u);
    }
  }

  // ---- switch to decoder weights; poll latent; dec h0 (tid<4 serial dot) ----
  for(int r=0;r<16;++r){
    const float* src = dec_Whh + ((size_t)((r&3)*HID + u4 + (r>>2)))*HID;
    *(float4*)(&W_lds[r*1024 + tid*4]) = *(const float4*)(src + tid*4);
  }
  if(tid < LZD+CDD) lat_lds[tid] = poll_val(&lat_tag[tid], 1u);
  __syncthreads();
  if(tid<4){
    const int j = u4 + tid;
    float s = lc_b[j];
    const float* wr = lc_W + (size_t)j*(LZD+CDD);
#pragma unroll 8
    for(int k=0;k<LZD+CDD;++k) s = fmaf(lat_lds[k], wr[k], s);
    creg = 0.0f;
    pub_val(&h_tag[j], s, DECTAG);   // slot 0, coalesced
  }

  // ---- decoder scan ----
  for(int t=0; t<SEQ; ++t){
    float pv = 0.f;
    if(l==0) pv = pre_dec[(size_t)t*G4 + gate*HID + u4 + ul];
    poll4(h_tag + (t&1)*HID, h_lds, tid, DECTAG + (unsigned)t);
    __syncthreads();                                  // B1
    float a0=0,a1=0,a2=0,a3=0;
    {
      const float* wr = &W_lds[g*1024 + l*4];
      const float* hr = &h_lds[l*4];
#pragma unroll
      for(int kk=0; kk<16; ++kk){
        float4 wv = *(const float4*)(wr + kk*64);
        float4 hv = *(const float4*)(hr + kk*64);
        a0 = fmaf(wv.x, hv.x, a0);
        a1 = fmaf(wv.y, hv.y, a1);
        a2 = fmaf(wv.z, hv.z, a2);
        a3 = fmaf(wv.w, hv.w, a3);
      }
    }
    float s = (a0+a1)+(a2+a3);
    s += __shfl_xor(s,1); s += __shfl_xor(s,2); s += __shfl_xor(s,4); s += __shfl_xor(s,8);
    if(l==0) gbuf[g] = s + pv;
    __syncthreads();                                  // B2
    if(tid<4){
      float gi=gbuf[tid*4+0], gf=gbuf[tid*4+1], gg=gbuf[tid*4+2], go=gbuf[tid*4+3];
      float cn = sigm(gf)*creg + sigm(gi)*tanhf(gg);
      float hn = sigm(go)*tanhf(cn);
      creg = cn;
      Hdec[(size_t)t*HID + u4 + tid] = hn;
      pub_val(&h_tag[((t+1)&1)*HID + u4+tid], hn, DECTAG + (unsigned)(t+1));
    }
  }
}

// ---------------- in-place log_softmax + first-index argmax ----------------
__global__ __launch_bounds__(256) void softmax_argmax(float* __restrict__ dist,
                                                      float* __restrict__ outTok)
{
  __shared__ float wm[4]; __shared__ int wi[4];
  __shared__ float s_max; __shared__ int s_idx; __shared__ float s_lz;
  const int t = blockIdx.x, tid = threadIdx.x;
  float* row = dist + (size_t)t*VOCAB;
  float m = -INFINITY; int idx = VOCAB;
  for(int i=tid; i<VOCAB; i+=256){
    float v = row[i];
    if(v > m){ m = v; idx = i; }
  }
  for(int d=1; d<64; d<<=1){
    float m2 = __shfl_xor(m, d); int i2 = __shfl_xor(idx, d);
    if(m2 > m || (m2 == m && i2 < idx)){ m = m2; idx = i2; }
  }
  if((tid&63)==0){ wm[tid>>6]=m; wi[tid>>6]=idx; }
  __syncthreads();
  if(tid==0){
    float mm = wm[0]; int ii = wi[0];
    for(int q=1;q<4;++q) if(wm[q]>mm || (wm[q]==mm && wi[q]<ii)){ mm=wm[q]; ii=wi[q]; }
    s_max = mm; s_idx = ii;
  }
  __syncthreads();
  const float M = s_max;
  float s = 0.f;
  for(int i=tid; i<VOCAB; i+=256) s += expf(row[i] - M);
  for(int d=1; d<64; d<<=1) s += __shfl_xor(s, d);
  if((tid&63)==0) wm[tid>>6] = s;
  __syncthreads();
  if(tid==0) s_lz = M + logf(wm[0]+wm[1]+wm[2]+wm[3]);
  __syncthreads();
  const float lz = s_lz;
  for(int i=tid; i<VOCAB; i+=256) row[i] -= lz;
  if(tid==0) outTok[t] = (float)s_idx;
}

// ---------------- launch ----------------
extern "C" void kernel_launch(void* const* d_in, const int* in_sizes, int n_in,
                              void* d_out, int out_size, void* d_ws, size_t ws_size,
                              hipStream_t stream)
{
  (void)in_sizes; (void)n_in; (void)out_size; (void)ws_size;
  const int*   tok      = (const int*)  d_in[0];
  const float* h0       = (const float*)d_in[1];
  const float* c0       = (const float*)d_in[2];
  const float* ccond    = (const float*)d_in[3];
  // d_in[4] = use_teacher_forcing (unused by reference body)
  const float* enc_emb  = (const float*)d_in[5];
  const float* enc_Wih  = (const float*)d_in[6];
  const float* enc_Whh  = (const float*)d_in[7];
  const float* enc_bih  = (const float*)d_in[8];
  const float* enc_bhh  = (const float*)d_in[9];
  const float* dec_emb  = (const float*)d_in[10];
  const float* dec_Wih  = (const float*)d_in[11];
  const float* dec_Whh  = (const float*)d_in[12];
  const float* dec_bih  = (const float*)d_in[13];
  const float* dec_bhh  = (const float*)d_in[14];
  const float* out_W    = (const float*)d_in[15];
  const float* out_b    = (const float*)d_in[16];
  const float* mean_W   = (const float*)d_in[17];
  const float* mean_b   = (const float*)d_in[18];
  const float* logvar_W = (const float*)d_in[19];
  const float* logvar_b = (const float*)d_in[20];
  const float* lc_W     = (const float*)d_in[21];
  const float* lc_b     = (const float*)d_in[22];

  float* ws      = (float*)d_ws;
  float* xenc    = ws;                       // 256*1024
  float* xdec    = xenc + SEQ*HID;           // 256*1024
  float* pre_enc = xdec + SEQ*HID;           // 256*4096
  float* pre_dec = pre_enc + (size_t)SEQ*G4; // 256*4096
  float* Hdec    = pre_dec + (size_t)SEQ*G4; // 256*1024
  ull*   tags    = (ull*)(Hdec + (size_t)SEQ*HID);  // 8B-aligned
  ull*   h_tag   = tags;                     // [2*1024]
  ull*   mlv_tag = h_tag + 2*HID;            // [256]
  ull*   lat_tag = mlv_tag + 2*LZD;          // [160]
  // total ~11.6 MB of ws

  float* out      = (float*)d_out;
  float* outTok   = out;                          // [256] tokens (as f32)
  float* dist     = out + SEQ;                    // [256,50257] log-softmax
  float* out_mean = dist + (size_t)SEQ*VOCAB;     // [128]
  float* out_lv   = out_mean + LZD;               // [128]

  hipLaunchKernelGGL(vae_embed, dim3(SEQ+1), dim3(256), 0, stream,
                     tok, enc_emb, dec_emb, xenc, xdec, tags);
  hipLaunchKernelGGL(gemm_pre, dim3(G4/64, SEQ/64, 2), dim3(256), 0, stream,
                     xenc, enc_Wih, enc_bih, enc_bhh,
                     xdec, dec_Wih, dec_bih, dec_bhh, pre_enc, pre_dec);
  hipLaunchKernelGGL(vae_scan, dim3(NWG), dim3(256), 0, stream,
                     enc_Whh, dec_Whh, pre_enc, pre_dec, h0, c0, ccond,
                     mean_W, mean_b, logvar_W, logvar_b, lc_W, lc_b,
                     h_tag, mlv_tag, lat_tag, Hdec, out_mean, out_lv);
  hipLaunchKernelGGL(gemm_nt_128, dim3((VOCAB+127)/128, SEQ/128), dim3(256), 0, stream,
                     Hdec, out_W, out_b, dist, HID, VOCAB);
  hipLaunchKernelGGL(softmax_argmax, dim3(SEQ), dim3(256), 0, stream, dist, outTok);
}

// Round 16
// 1746.572 us; speedup vs baseline: 1.2741x; 1.0693x over previous
//
#include <hip/hip_runtime.h>
#include <math.h>

#define VOCAB 50257
#define HID   1024
#define G4    4096
#define LZD   128
#define CDD   32
#define SEQ   256
#define NWG   256          // scan WGs: WG q owns h-units 4q..4q+3
#define DECTAG 300u        // decoder tag base (disjoint from encoder tags 1..256)

typedef unsigned long long ull;
typedef __attribute__((ext_vector_type(8))) short bf16x8;
typedef __attribute__((ext_vector_type(4))) float f32x4;

// ---------------- helpers ----------------
__device__ __forceinline__ float sigm(float x){ return 1.0f/(1.0f+expf(-x)); }

__device__ __forceinline__ unsigned short f2bf(float x){   // fp32 -> bf16 RNE
  unsigned u = __float_as_uint(x);
  unsigned r = u + 0x7FFFu + ((u>>16)&1u);
  return (unsigned short)(r>>16);
}
__device__ __forceinline__ float bf2f(unsigned short h){
  return __uint_as_float(((unsigned)h)<<16);
}

// tagged-word protocol: 64-bit relaxed agent atomic = (tag<<32)|float_bits.
__device__ __forceinline__ void pub_val(ull* p, float x, unsigned tag){
  ull v = ((ull)tag<<32) | (ull)__float_as_uint(x);
  __hip_atomic_store(p, v, __ATOMIC_RELAXED, __HIP_MEMORY_SCOPE_AGENT);
}
__device__ __forceinline__ ull ald(ull* p){
  return __hip_atomic_load(p, __ATOMIC_RELAXED, __HIP_MEMORY_SCOPE_AGENT);
}
__device__ __forceinline__ float poll_val(ull* p, unsigned tag){
  ull v = ald(p);
  while((unsigned)(v>>32) != tag){ __builtin_amdgcn_s_sleep(1); v = ald(p); }
  return __uint_as_float((unsigned)v);
}
// all-thread poll of 4 strided words; ALL stale words re-issued in parallel each
// iteration (1 LLC RTT per round). [R13-verified −190µs]
__device__ __forceinline__ void poll4(ull* slot, float* hb, int tid, unsigned tag){
  ull *p0=&slot[tid], *p1=&slot[tid+256], *p2=&slot[tid+512], *p3=&slot[tid+768];
  ull v0=ald(p0), v1=ald(p1), v2=ald(p2), v3=ald(p3);
  for(;;){
    const bool o0=((unsigned)(v0>>32)==tag), o1=((unsigned)(v1>>32)==tag);
    const bool o2=((unsigned)(v2>>32)==tag), o3=((unsigned)(v3>>32)==tag);
    if(o0 & o1 & o2 & o3) break;
    __builtin_amdgcn_s_sleep(1);
    if(!o0) v0=ald(p0);
    if(!o1) v1=ald(p1);
    if(!o2) v2=ald(p2);
    if(!o3) v3=ald(p3);
  }
  hb[tid]     = __uint_as_float((unsigned)v0);
  hb[tid+256] = __uint_as_float((unsigned)v1);
  hb[tid+512] = __uint_as_float((unsigned)v2);
  hb[tid+768] = __uint_as_float((unsigned)v3);
}

// JAX uniform bits -> sqrt(2)*erfinv (Giles poly, == XLA f32 ErfInv)
__device__ __forceinline__ float eps_from_bits(unsigned bits){
  float f = __uint_as_float((bits>>9) | 0x3F800000u) - 1.0f;
  const float MINV = -0.99999994f;
  float u = fmaxf(MINV, f*2.0f + MINV);
  float w = -log1pf(-u*u);
  float p;
  if(w < 5.0f){
    w -= 2.5f;
    p =  2.81022636e-08f;
    p = fmaf(p,w, 3.43273939e-07f);
    p = fmaf(p,w,-3.5233877e-06f);
    p = fmaf(p,w,-4.39150654e-06f);
    p = fmaf(p,w, 0.00021858087f);
    p = fmaf(p,w,-0.00125372503f);
    p = fmaf(p,w,-0.00417768164f);
    p = fmaf(p,w, 0.246640727f);
    p = fmaf(p,w, 1.50140941f);
  }else{
    w = sqrtf(w) - 3.0f;
    p = -0.000200214257f;
    p = fmaf(p,w, 0.000100950558f);
    p = fmaf(p,w, 0.00134934322f);
    p = fmaf(p,w,-0.00367342844f);
    p = fmaf(p,w, 0.00573950773f);
    p = fmaf(p,w,-0.0076224613f);
    p = fmaf(p,w, 0.00943887047f);
    p = fmaf(p,w, 1.00167406f);
    p = fmaf(p,w, 2.83297682f);
  }
  return 1.4142135623730951f * (p*u);
}

// ---------------- prep: gathers + tag reset ----------------
__global__ __launch_bounds__(256) void vae_embed(
    const int* __restrict__ tok, const float* __restrict__ enc_emb,
    const float* __restrict__ dec_emb,
    float* __restrict__ xenc, float* __restrict__ xdec, ull* __restrict__ tags)
{
  const int b = blockIdx.x, tid = threadIdx.x;
  if(b == SEQ){
    for(int i=tid; i<2*HID+2*LZD+LZD+CDD; i+=256)
      __hip_atomic_store(&tags[i], 0ULL, __ATOMIC_RELAXED, __HIP_MEMORY_SCOPE_AGENT);
    return;
  }
  const int te = tok[b];
  const int td = (b==0) ? 0 : tok[b-1];                   // SOS = 0
  float4 v = *(const float4*)(enc_emb + (size_t)te*HID + tid*4);
  *(float4*)(xenc + (size_t)b*HID + tid*4) = v;
  float4 u = *(const float4*)(dec_emb + (size_t)td*HID + tid*4);
  u.x=fmaxf(u.x,0.f); u.y=fmaxf(u.y,0.f); u.z=fmaxf(u.z,0.f); u.w=fmaxf(u.w,0.f);
  *(float4*)(xdec + (size_t)b*HID + tid*4) = u;
}

// ---------------- merged pre-GEMM: z=0 enc, z=1 dec. C[M,G4] = X @ Wih^T + bih + bhh ----
__global__ __launch_bounds__(256) void gemm_pre(
    const float* __restrict__ xe, const float* __restrict__ Wihe,
    const float* __restrict__ be1, const float* __restrict__ be2,
    const float* __restrict__ xd, const float* __restrict__ Wihd,
    const float* __restrict__ bd1, const float* __restrict__ bd2,
    float* __restrict__ preE, float* __restrict__ preD)
{
  const int z = blockIdx.z;
  const float* A  = z ? xd   : xe;
  const float* B  = z ? Wihd : Wihe;
  const float* b1 = z ? bd1  : be1;
  const float* b2 = z ? bd2  : be2;
  float* C        = z ? preD : preE;
  const int K = HID, N = G4;

  __shared__ float As[16*68];
  __shared__ float Bs[16*68];
  const int tid = threadIdx.x;
  const int bn = blockIdx.x<<6, bm = blockIdx.y<<6;
  const int lr = tid>>2, lc4 = (tid&3)<<2;
  const int tx = tid&15, ty = tid>>4;
  const float* Arow = A + (size_t)(bm+lr)*K + lc4;
  const float* Brow = B + (size_t)(bn+lr)*K + lc4;
  float acc[4][4] = {};
  for(int kt=0; kt<K; kt+=16){
    float4 av = *(const float4*)(Arow + kt);
    float4 bv = *(const float4*)(Brow + kt);
    __syncthreads();
    As[(lc4+0)*68+lr]=av.x; As[(lc4+1)*68+lr]=av.y; As[(lc4+2)*68+lr]=av.z; As[(lc4+3)*68+lr]=av.w;
    Bs[(lc4+0)*68+lr]=bv.x; Bs[(lc4+1)*68+lr]=bv.y; Bs[(lc4+2)*68+lr]=bv.z; Bs[(lc4+3)*68+lr]=bv.w;
    __syncthreads();
#pragma unroll
    for(int k=0;k<16;++k){
      float4 a = *(const float4*)(As + k*68 + (ty<<2));
      float4 b = *(const float4*)(Bs + k*68 + (tx<<2));
      float a4[4] = {a.x,a.y,a.z,a.w};
      float b4[4] = {b.x,b.y,b.z,b.w};
#pragma unroll
      for(int i=0;i<4;++i)
#pragma unroll
        for(int j=0;j<4;++j)
          acc[i][j] = fmaf(a4[i], b4[j], acc[i][j]);
    }
  }
  const int n0 = bn + (tx<<2);
#pragma unroll
  for(int i=0;i<4;++i){
    const int m = bm + (ty<<2) + i;
#pragma unroll
    for(int j=0;j<4;++j){
      const int n = n0+j;
      C[(size_t)m*N + n] = acc[i][j] + b1[n] + b2[n];
    }
  }
}

// ---------------- logits GEMM: split-bf16 MFMA (hi·hi + hi·lo + lo·hi) ----------------
// C[256,N] = A[256,K] @ B[N,K]^T + bias.  128x128 tile, BK=32, 4 waves (2x2),
// per wave 4x4 fragments of mfma_f32_16x16x32_bf16 (3 passes per fragment).
// A-frag: row = lane&15, k = (lane>>4)*8 + j (8 contiguous bf16).
// C/D  : col = lane&15, row = (lane>>4)*4 + reg  [m89-verified].
__global__ __launch_bounds__(256) void gemm_logits_mfma(
    const float* __restrict__ A, const float* __restrict__ B,
    const float* __restrict__ bias, float* __restrict__ C, int K, int N)
{
  __shared__ unsigned short Ah[128][40], Al[128][40];   // bf16 hi/lo, pad 40 (80B rows, 16B-aligned)
  __shared__ unsigned short Bh[128][40], Bl[128][40];
  const int tid = threadIdx.x;
  const int bn = blockIdx.x<<7, bm = blockIdx.y<<7;
  const int wid = tid>>6, lane = tid&63;
  const int wr = wid>>1, wc = wid&1;          // wave 2x2 grid, each 64x64
  const int l15 = lane&15, l4 = lane>>4;
  const int sr = tid>>1, sc0 = (tid&1)<<4;    // staging: row, col-offset (0/16)
  const bool bok = (bn+sr) < N;
  const float* Asrc = A + (size_t)(bm+sr)*K + sc0;
  const float* Bsrc = B + (size_t)(bn+sr)*K + sc0;

  f32x4 acc[4][4] = {};

  for(int kt=0; kt<K; kt+=32){
    __syncthreads();
#pragma unroll
    for(int j=0;j<16;j+=2){
      float2 v = *(const float2*)(Asrc + kt + j);
      unsigned short hx=f2bf(v.x), hy=f2bf(v.y);
      unsigned short lx=f2bf(v.x - bf2f(hx)), ly=f2bf(v.y - bf2f(hy));
      *(unsigned*)&Ah[sr][sc0+j] = ((unsigned)hy<<16)|hx;
      *(unsigned*)&Al[sr][sc0+j] = ((unsigned)ly<<16)|lx;
    }
#pragma unroll
    for(int j=0;j<16;j+=2){
      float2 v = bok ? *(const float2*)(Bsrc + kt + j) : make_float2(0.f,0.f);
      unsigned short hx=f2bf(v.x), hy=f2bf(v.y);
      unsigned short lx=f2bf(v.x - bf2f(hx)), ly=f2bf(v.y - bf2f(hy));
      *(unsigned*)&Bh[sr][sc0+j] = ((unsigned)hy<<16)|hx;
      *(unsigned*)&Bl[sr][sc0+j] = ((unsigned)ly<<16)|lx;
    }
    __syncthreads();
    bf16x8 aH[4],aL[4],bH[4],bL[4];
#pragma unroll
    for(int f=0; f<4; ++f){
      const int ar = wr*64 + f*16 + l15;
      aH[f] = *(const bf16x8*)&Ah[ar][l4*8];
      aL[f] = *(const bf16x8*)&Al[ar][l4*8];
      const int br = wc*64 + f*16 + l15;
      bH[f] = *(const bf16x8*)&Bh[br][l4*8];
      bL[f] = *(const bf16x8*)&Bl[br][l4*8];
    }
#pragma unroll
    for(int i=0;i<4;++i)
#pragma unroll
      for(int j=0;j<4;++j){
        acc[i][j] = __builtin_amdgcn_mfma_f32_16x16x32_bf16(aH[i], bH[j], acc[i][j], 0,0,0);
        acc[i][j] = __builtin_amdgcn_mfma_f32_16x16x32_bf16(aH[i], bL[j], acc[i][j], 0,0,0);
        acc[i][j] = __builtin_amdgcn_mfma_f32_16x16x32_bf16(aL[i], bH[j], acc[i][j], 0,0,0);
      }
  }

#pragma unroll
  for(int i=0;i<4;++i){
#pragma unroll
    for(int j=0;j<4;++j){
      const int col = bn + wc*64 + j*16 + l15;
      if(col < N){
        const float bb = bias[col];
        const int row0 = bm + wr*64 + i*16 + l4*4;
#pragma unroll
        for(int r=0;r<4;++r)
          C[(size_t)(row0+r)*N + col] = acc[i][j][r] + bb;
      }
    }
  }
}

// ---------------- persistent scan: R13 champion (UNCHANGED — control) ----------------
__global__ __launch_bounds__(256,1) void vae_scan(
    const float* __restrict__ enc_Whh, const float* __restrict__ dec_Whh,
    const float* __restrict__ pre_enc, const float* __restrict__ pre_dec,
    const float* __restrict__ h0in, const float* __restrict__ c0in,
    const float* __restrict__ ccond,
    const float* __restrict__ mean_W, const float* __restrict__ mean_b,
    const float* __restrict__ logvar_W, const float* __restrict__ logvar_b,
    const float* __restrict__ lc_W, const float* __restrict__ lc_b,
    ull* __restrict__ h_tag, ull* __restrict__ mlv_tag, ull* __restrict__ lat_tag,
    float* __restrict__ Hdec, float* __restrict__ out_mean, float* __restrict__ out_logvar)
{
  __shared__ float W_lds[16*1024];   // 64 KB, current phase
  __shared__ float h_lds[HID];
  __shared__ float lat_lds[LZD+CDD];
  __shared__ float sh_mlv[2*LZD];
  __shared__ float gbuf[16];
  __shared__ float redb[4];

  const int q = blockIdx.x, tid = threadIdx.x;
  const int g = tid>>4, l = tid&15;     // 16 groups x 16 lanes
  const int gate = g&3, ul = g>>2;
  const int u4 = 4*q;

  // ---- load encoder W_hh slice (conflict-free 16-lane-row layout) ----
  for(int r=0;r<16;++r){
    const float* src = enc_Whh + ((size_t)((r&3)*HID + u4 + (r>>2)))*HID;
    *(float4*)(&W_lds[r*1024 + tid*4]) = *(const float4*)(src + tid*4);
  }
  float creg = (tid<4) ? c0in[u4+tid] : 0.0f;

  // ---- encoder scan (2 barriers/step) ----
  for(int t=0; t<SEQ; ++t){
    float pv = 0.f;
    if(l==0) pv = pre_enc[(size_t)t*G4 + gate*HID + u4 + ul];  // issue-early
    if(t==0){
#pragma unroll
      for(int j=0;j<4;++j) h_lds[tid+j*256] = h0in[tid+j*256];
    }else{
      poll4(h_tag + (t&1)*HID, h_lds, tid, (unsigned)t);
    }
    __syncthreads();                                  // B1
    float a0=0,a1=0,a2=0,a3=0;
    {
      const float* wr = &W_lds[g*1024 + l*4];
      const float* hr = &h_lds[l*4];
#pragma unroll
      for(int kk=0; kk<16; ++kk){
        float4 wv = *(const float4*)(wr + kk*64);
        float4 hv = *(const float4*)(hr + kk*64);
        a0 = fmaf(wv.x, hv.x, a0);
        a1 = fmaf(wv.y, hv.y, a1);
        a2 = fmaf(wv.z, hv.z, a2);
        a3 = fmaf(wv.w, hv.w, a3);
      }
    }
    float s = (a0+a1)+(a2+a3);
    s += __shfl_xor(s,1); s += __shfl_xor(s,2); s += __shfl_xor(s,4); s += __shfl_xor(s,8);
    if(l==0) gbuf[g] = s + pv;
    __syncthreads();                                  // B2
    if(tid<4){
      float gi=gbuf[tid*4+0], gf=gbuf[tid*4+1], gg=gbuf[tid*4+2], go=gbuf[tid*4+3];
      float cn = sigm(gf)*creg + sigm(gi)*tanhf(gg);
      float hn = sigm(go)*tanhf(cn);
      creg = cn;
      pub_val(&h_tag[((t+1)&1)*HID + u4+tid], hn, (unsigned)(t+1));  // 1 coalesced 32B store
    }
  }

  // ---- mean/logvar: WG q computes row q of [mean;logvar]; h_enc = slot0 tag 256 ----
  {
    poll4(h_tag, h_lds, tid, (unsigned)SEQ);
    __syncthreads();
    const float* Wrow = (q < LZD) ? (mean_W + (size_t)q*HID)
                                  : (logvar_W + (size_t)(q-LZD)*HID);
    const float bias = (q < LZD) ? mean_b[q] : logvar_b[q-LZD];
    float4 hv = *(const float4*)(h_lds + tid*4);
    float4 wv = *(const float4*)(Wrow + tid*4);
    float p = hv.x*wv.x + hv.y*wv.y + hv.z*wv.z + hv.w*wv.w;
    p += __shfl_xor(p,1); p += __shfl_xor(p,2); p += __shfl_xor(p,4);
    p += __shfl_xor(p,8); p += __shfl_xor(p,16); p += __shfl_xor(p,32);
    if((tid&63)==0) redb[tid>>6] = p;
    __syncthreads();
    if(tid==0){
      float s = redb[0]+redb[1]+redb[2]+redb[3] + bias;
      pub_val(&mlv_tag[q], s, 1u);
      if(q < LZD) out_mean[q] = s; else out_logvar[q-LZD] = s;
    }
  }

  // ---- WG0: partitionable-threefry eps + latent ----
  if(q==0){
    sh_mlv[tid] = poll_val(&mlv_tag[tid], 1u);
    __syncthreads();
    if(tid < LZD){
      unsigned x0 = 0u, x1 = (unsigned)tid;          // counter (0, i)
      const unsigned ks[3] = {0u, 1u, 0x1BD11BDAu ^ 0u ^ 1u};  // key(1)
      x0 += ks[0]; x1 += ks[1];
      const int RA[4] = {13,15,26,6}, RB[4] = {17,29,16,24};
#pragma unroll
      for(int gg2=0; gg2<5; ++gg2){
        const int* R = (gg2&1) ? RB : RA;
#pragma unroll
        for(int qq=0;qq<4;++qq){
          x0 += x1;
          x1 = (x1 << R[qq]) | (x1 >> (32-R[qq]));
          x1 ^= x0;
        }
        x0 += ks[(gg2+1)%3];
        x1 += ks[(gg2+2)%3] + (unsigned)(gg2+1);
      }
      float e = eps_from_bits(x0 ^ x1);
      pub_val(&lat_tag[tid], fmaf(e, expf(0.5f*sh_mlv[LZD+tid]), sh_mlv[tid]), 1u);
    } else if(tid < LZD+CDD){
      pub_val(&lat_tag[tid], ccond[tid-LZD], 1u);
    }
  }

  // ---- switch to decoder weights; poll latent; dec h0 (tid<4 serial dot) ----
  for(int r=0;r<16;++r){
    const float* src = dec_Whh + ((size_t)((r&3)*HID + u4 + (r>>2)))*HID;
    *(float4*)(&W_lds[r*1024 + tid*4]) = *(const float4*)(src + tid*4);
  }
  if(tid < LZD+CDD) lat_lds[tid] = poll_val(&lat_tag[tid], 1u);
  __syncthreads();
  if(tid<4){
    const int j = u4 + tid;
    float s = lc_b[j];
    const float* wr = lc_W + (size_t)j*(LZD+CDD);
#pragma unroll 8
    for(int k=0;k<LZD+CDD;++k) s = fmaf(lat_lds[k], wr[k], s);
    creg = 0.0f;
    pub_val(&h_tag[j], s, DECTAG);   // slot 0, coalesced
  }

  // ---- decoder scan ----
  for(int t=0; t<SEQ; ++t){
    float pv = 0.f;
    if(l==0) pv = pre_dec[(size_t)t*G4 + gate*HID + u4 + ul];
    poll4(h_tag + (t&1)*HID, h_lds, tid, DECTAG + (unsigned)t);
    __syncthreads();                                  // B1
    float a0=0,a1=0,a2=0,a3=0;
    {
      const float* wr = &W_lds[g*1024 + l*4];
      const float* hr = &h_lds[l*4];
#pragma unroll
      for(int kk=0; kk<16; ++kk){
        float4 wv = *(const float4*)(wr + kk*64);
        float4 hv = *(const float4*)(hr + kk*64);
        a0 = fmaf(wv.x, hv.x, a0);
        a1 = fmaf(wv.y, hv.y, a1);
        a2 = fmaf(wv.z, hv.z, a2);
        a3 = fmaf(wv.w, hv.w, a3);
      }
    }
    float s = (a0+a1)+(a2+a3);
    s += __shfl_xor(s,1); s += __shfl_xor(s,2); s += __shfl_xor(s,4); s += __shfl_xor(s,8);
    if(l==0) gbuf[g] = s + pv;
    __syncthreads();                                  // B2
    if(tid<4){
      float gi=gbuf[tid*4+0], gf=gbuf[tid*4+1], gg=gbuf[tid*4+2], go=gbuf[tid*4+3];
      float cn = sigm(gf)*creg + sigm(gi)*tanhf(gg);
      float hn = sigm(go)*tanhf(cn);
      creg = cn;
      Hdec[(size_t)t*HID + u4 + tid] = hn;
      pub_val(&h_tag[((t+1)&1)*HID + u4+tid], hn, DECTAG + (unsigned)(t+1));
    }
  }
}

// ---------------- in-place log_softmax + first-index argmax ----------------
__global__ __launch_bounds__(256) void softmax_argmax(float* __restrict__ dist,
                                                      float* __restrict__ outTok)
{
  __shared__ float wm[4]; __shared__ int wi[4];
  __shared__ float s_max; __shared__ int s_idx; __shared__ float s_lz;
  const int t = blockIdx.x, tid = threadIdx.x;
  float* row = dist + (size_t)t*VOCAB;
  float m = -INFINITY; int idx = VOCAB;
  for(int i=tid; i<VOCAB; i+=256){
    float v = row[i];
    if(v > m){ m = v; idx = i; }
  }
  for(int d=1; d<64; d<<=1){
    float m2 = __shfl_xor(m, d); int i2 = __shfl_xor(idx, d);
    if(m2 > m || (m2 == m && i2 < idx)){ m = m2; idx = i2; }
  }
  if((tid&63)==0){ wm[tid>>6]=m; wi[tid>>6]=idx; }
  __syncthreads();
  if(tid==0){
    float mm = wm[0]; int ii = wi[0];
    for(int q=1;q<4;++q) if(wm[q]>mm || (wm[q]==mm && wi[q]<ii)){ mm=wm[q]; ii=wi[q]; }
    s_max = mm; s_idx = ii;
  }
  __syncthreads();
  const float M = s_max;
  float s = 0.f;
  for(int i=tid; i<VOCAB; i+=256) s += expf(row[i] - M);
  for(int d=1; d<64; d<<=1) s += __shfl_xor(s, d);
  if((tid&63)==0) wm[tid>>6] = s;
  __syncthreads();
  if(tid==0) s_lz = M + logf(wm[0]+wm[1]+wm[2]+wm[3]);
  __syncthreads();
  const float lz = s_lz;
  for(int i=tid; i<VOCAB; i+=256) row[i] -= lz;
  if(tid==0) outTok[t] = (float)s_idx;
}

// ---------------- launch ----------------
extern "C" void kernel_launch(void* const* d_in, const int* in_sizes, int n_in,
                              void* d_out, int out_size, void* d_ws, size_t ws_size,
                              hipStream_t stream)
{
  (void)in_sizes; (void)n_in; (void)out_size; (void)ws_size;
  const int*   tok      = (const int*)  d_in[0];
  const float* h0       = (const float*)d_in[1];
  const float* c0       = (const float*)d_in[2];
  const float* ccond    = (const float*)d_in[3];
  // d_in[4] = use_teacher_forcing (unused by reference body)
  const float* enc_emb  = (const float*)d_in[5];
  const float* enc_Wih  = (const float*)d_in[6];
  const float* enc_Whh  = (const float*)d_in[7];
  const float* enc_bih  = (const float*)d_in[8];
  const float* enc_bhh  = (const float*)d_in[9];
  const float* dec_emb  = (const float*)d_in[10];
  const float* dec_Wih  = (const float*)d_in[11];
  const float* dec_Whh  = (const float*)d_in[12];
  const float* dec_bih  = (const float*)d_in[13];
  const float* dec_bhh  = (const float*)d_in[14];
  const float* out_W    = (const float*)d_in[15];
  const float* out_b    = (const float*)d_in[16];
  const float* mean_W   = (const float*)d_in[17];
  const float* mean_b   = (const float*)d_in[18];
  const float* logvar_W = (const float*)d_in[19];
  const float* logvar_b = (const float*)d_in[20];
  const float* lc_W     = (const float*)d_in[21];
  const float* lc_b     = (const float*)d_in[22];

  float* ws      = (float*)d_ws;
  float* xenc    = ws;                       // 256*1024
  float* xdec    = xenc + SEQ*HID;           // 256*1024
  float* pre_enc = xdec + SEQ*HID;           // 256*4096
  float* pre_dec = pre_enc + (size_t)SEQ*G4; // 256*4096
  float* Hdec    = pre_dec + (size_t)SEQ*G4; // 256*1024
  ull*   tags    = (ull*)(Hdec + (size_t)SEQ*HID);  // 8B-aligned
  ull*   h_tag   = tags;                     // [2*1024]
  ull*   mlv_tag = h_tag + 2*HID;            // [256]
  ull*   lat_tag = mlv_tag + 2*LZD;          // [160]
  // total ~11.6 MB of ws

  float* out      = (float*)d_out;
  float* outTok   = out;                          // [256] tokens (as f32)
  float* dist     = out + SEQ;                    // [256,50257] log-softmax
  float* out_mean = dist + (size_t)SEQ*VOCAB;     // [128]
  float* out_lv   = out_mean + LZD;               // [128]

  hipLaunchKernelGGL(vae_embed, dim3(SEQ+1), dim3(256), 0, stream,
                     tok, enc_emb, dec_emb, xenc, xdec, tags);
  hipLaunchKernelGGL(gemm_pre, dim3(G4/64, SEQ/64, 2), dim3(256), 0, stream,
                     xenc, enc_Wih, enc_bih, enc_bhh,
                     xdec, dec_Wih, dec_bih, dec_bhh, pre_enc, pre_dec);
  hipLaunchKernelGGL(vae_scan, dim3(NWG), dim3(256), 0, stream,
                     enc_Whh, dec_Whh, pre_enc, pre_dec, h0, c0, ccond,
                     mean_W, mean_b, logvar_W, logvar_b, lc_W, lc_b,
                     h_tag, mlv_tag, lat_tag, Hdec, out_mean, out_lv);
  hipLaunchKernelGGL(gemm_logits_mfma, dim3((VOCAB+127)/128, SEQ/128), dim3(256), 0, stream,
                     Hdec, out_W, out_b, dist, HID, VOCAB);
  hipLaunchKernelGGL(softmax_argmax, dim3(SEQ), dim3(256), 0, stream, dist, outTok);
}

// Round 17
// 1693.139 us; speedup vs baseline: 1.3143x; 1.0316x over previous
//
#include <hip/hip_runtime.h>
#include <math.h>

#define VOCAB 50257
#define HID   1024
#define G4    4096
#define LZD   128
#define CDD   32
#define SEQ   256
#define NWG   256          // scan WGs: WG q owns h-units 4q..4q+3
#define DECTAG 300u        // decoder tag base (disjoint from encoder tags 1..256)

typedef unsigned long long ull;
typedef __attribute__((ext_vector_type(8))) short bf16x8;
typedef __attribute__((ext_vector_type(4))) float f32x4;

// ---------------- helpers ----------------
__device__ __forceinline__ float sigm(float x){ return 1.0f/(1.0f+expf(-x)); }

__device__ __forceinline__ unsigned short f2bf(float x){   // fp32 -> bf16 RNE
  unsigned u = __float_as_uint(x);
  unsigned r = u + 0x7FFFu + ((u>>16)&1u);
  return (unsigned short)(r>>16);
}
__device__ __forceinline__ float bf2f(unsigned short h){
  return __uint_as_float(((unsigned)h)<<16);
}

// tagged-word protocol: 64-bit relaxed agent atomic = (tag<<32)|float_bits.
__device__ __forceinline__ void pub_val(ull* p, float x, unsigned tag){
  ull v = ((ull)tag<<32) | (ull)__float_as_uint(x);
  __hip_atomic_store(p, v, __ATOMIC_RELAXED, __HIP_MEMORY_SCOPE_AGENT);
}
__device__ __forceinline__ ull ald(ull* p){
  return __hip_atomic_load(p, __ATOMIC_RELAXED, __HIP_MEMORY_SCOPE_AGENT);
}
__device__ __forceinline__ float poll_val(ull* p, unsigned tag){
  ull v = ald(p);
  while((unsigned)(v>>32) != tag){ __builtin_amdgcn_s_sleep(1); v = ald(p); }
  return __uint_as_float((unsigned)v);
}
// all-thread poll of 4 strided words; ALL stale words re-issued in parallel each
// iteration (1 LLC RTT per round). [R13-verified −190µs]
__device__ __forceinline__ void poll4(ull* slot, float* hb, int tid, unsigned tag){
  ull *p0=&slot[tid], *p1=&slot[tid+256], *p2=&slot[tid+512], *p3=&slot[tid+768];
  ull v0=ald(p0), v1=ald(p1), v2=ald(p2), v3=ald(p3);
  for(;;){
    const bool o0=((unsigned)(v0>>32)==tag), o1=((unsigned)(v1>>32)==tag);
    const bool o2=((unsigned)(v2>>32)==tag), o3=((unsigned)(v3>>32)==tag);
    if(o0 & o1 & o2 & o3) break;
    __builtin_amdgcn_s_sleep(1);
    if(!o0) v0=ald(p0);
    if(!o1) v1=ald(p1);
    if(!o2) v2=ald(p2);
    if(!o3) v3=ald(p3);
  }
  hb[tid]     = __uint_as_float((unsigned)v0);
  hb[tid+256] = __uint_as_float((unsigned)v1);
  hb[tid+512] = __uint_as_float((unsigned)v2);
  hb[tid+768] = __uint_as_float((unsigned)v3);
}

// JAX uniform bits -> sqrt(2)*erfinv (Giles poly, == XLA f32 ErfInv)
__device__ __forceinline__ float eps_from_bits(unsigned bits){
  float f = __uint_as_float((bits>>9) | 0x3F800000u) - 1.0f;
  const float MINV = -0.99999994f;
  float u = fmaxf(MINV, f*2.0f + MINV);
  float w = -log1pf(-u*u);
  float p;
  if(w < 5.0f){
    w -= 2.5f;
    p =  2.81022636e-08f;
    p = fmaf(p,w, 3.43273939e-07f);
    p = fmaf(p,w,-3.5233877e-06f);
    p = fmaf(p,w,-4.39150654e-06f);
    p = fmaf(p,w, 0.00021858087f);
    p = fmaf(p,w,-0.00125372503f);
    p = fmaf(p,w,-0.00417768164f);
    p = fmaf(p,w, 0.246640727f);
    p = fmaf(p,w, 1.50140941f);
  }else{
    w = sqrtf(w) - 3.0f;
    p = -0.000200214257f;
    p = fmaf(p,w, 0.000100950558f);
    p = fmaf(p,w, 0.00134934322f);
    p = fmaf(p,w,-0.00367342844f);
    p = fmaf(p,w, 0.00573950773f);
    p = fmaf(p,w,-0.0076224613f);
    p = fmaf(p,w, 0.00943887047f);
    p = fmaf(p,w, 1.00167406f);
    p = fmaf(p,w, 2.83297682f);
  }
  return 1.4142135623730951f * (p*u);
}

// ---------------- prep: gathers + tag reset ----------------
__global__ __launch_bounds__(256) void vae_embed(
    const int* __restrict__ tok, const float* __restrict__ enc_emb,
    const float* __restrict__ dec_emb,
    float* __restrict__ xenc, float* __restrict__ xdec, ull* __restrict__ tags)
{
  const int b = blockIdx.x, tid = threadIdx.x;
  if(b == SEQ){
    for(int i=tid; i<2*HID+2*LZD+LZD+CDD; i+=256)
      __hip_atomic_store(&tags[i], 0ULL, __ATOMIC_RELAXED, __HIP_MEMORY_SCOPE_AGENT);
    return;
  }
  const int te = tok[b];
  const int td = (b==0) ? 0 : tok[b-1];                   // SOS = 0
  float4 v = *(const float4*)(enc_emb + (size_t)te*HID + tid*4);
  *(float4*)(xenc + (size_t)b*HID + tid*4) = v;
  float4 u = *(const float4*)(dec_emb + (size_t)td*HID + tid*4);
  u.x=fmaxf(u.x,0.f); u.y=fmaxf(u.y,0.f); u.z=fmaxf(u.z,0.f); u.w=fmaxf(u.w,0.f);
  *(float4*)(xdec + (size_t)b*HID + tid*4) = u;
}

// ---------------- merged pre-GEMM: z=0 enc, z=1 dec. C[M,G4] = X @ Wih^T + bih + bhh ----
__global__ __launch_bounds__(256) void gemm_pre(
    const float* __restrict__ xe, const float* __restrict__ Wihe,
    const float* __restrict__ be1, const float* __restrict__ be2,
    const float* __restrict__ xd, const float* __restrict__ Wihd,
    const float* __restrict__ bd1, const float* __restrict__ bd2,
    float* __restrict__ preE, float* __restrict__ preD)
{
  const int z = blockIdx.z;
  const float* A  = z ? xd   : xe;
  const float* B  = z ? Wihd : Wihe;
  const float* b1 = z ? bd1  : be1;
  const float* b2 = z ? bd2  : be2;
  float* C        = z ? preD : preE;
  const int K = HID, N = G4;

  __shared__ float As[16*68];
  __shared__ float Bs[16*68];
  const int tid = threadIdx.x;
  const int bn = blockIdx.x<<6, bm = blockIdx.y<<6;
  const int lr = tid>>2, lc4 = (tid&3)<<2;
  const int tx = tid&15, ty = tid>>4;
  const float* Arow = A + (size_t)(bm+lr)*K + lc4;
  const float* Brow = B + (size_t)(bn+lr)*K + lc4;
  float acc[4][4] = {};
  for(int kt=0; kt<K; kt+=16){
    float4 av = *(const float4*)(Arow + kt);
    float4 bv = *(const float4*)(Brow + kt);
    __syncthreads();
    As[(lc4+0)*68+lr]=av.x; As[(lc4+1)*68+lr]=av.y; As[(lc4+2)*68+lr]=av.z; As[(lc4+3)*68+lr]=av.w;
    Bs[(lc4+0)*68+lr]=bv.x; Bs[(lc4+1)*68+lr]=bv.y; Bs[(lc4+2)*68+lr]=bv.z; Bs[(lc4+3)*68+lr]=bv.w;
    __syncthreads();
#pragma unroll
    for(int k=0;k<16;++k){
      float4 a = *(const float4*)(As + k*68 + (ty<<2));
      float4 b = *(const float4*)(Bs + k*68 + (tx<<2));
      float a4[4] = {a.x,a.y,a.z,a.w};
      float b4[4] = {b.x,b.y,b.z,b.w};
#pragma unroll
      for(int i=0;i<4;++i)
#pragma unroll
        for(int j=0;j<4;++j)
          acc[i][j] = fmaf(a4[i], b4[j], acc[i][j]);
    }
  }
  const int n0 = bn + (tx<<2);
#pragma unroll
  for(int i=0;i<4;++i){
    const int m = bm + (ty<<2) + i;
#pragma unroll
    for(int j=0;j<4;++j){
      const int n = n0+j;
      C[(size_t)m*N + n] = acc[i][j] + b1[n] + b2[n];
    }
  }
}

// ---------------- logits GEMM: split-bf16 MFMA, 256x128 tile (B read once) ----------------
// C[256,N] = A[256,K] @ B[N,K]^T + bias.  512 thr / 8 waves in 4x2 grid (64x64 each),
// BK=32, per wave 4x4 fragments of mfma_f32_16x16x32_bf16, 3 passes (hi·hi+hi·lo+lo·hi).
// A-frag: row = lane&15, k = (lane>>4)*8 + j.  C/D: col = lane&15, row = (lane>>4)*4+reg.
__global__ __launch_bounds__(512) void gemm_logits_mfma(
    const float* __restrict__ A, const float* __restrict__ B,
    const float* __restrict__ bias, float* __restrict__ C, int K, int N)
{
  __shared__ unsigned short Ah[256][40], Al[256][40];   // 20 KB each
  __shared__ unsigned short Bh[128][40], Bl[128][40];   // 10 KB each
  const int tid = threadIdx.x;
  const int bn = blockIdx.x<<7;
  const int wid = tid>>6, lane = tid&63;
  const int wr = wid>>1, wc = wid&1;          // 4x2 wave grid, each 64x64
  const int l15 = lane&15, l4 = lane>>4;
  const int asr = tid>>1, asc = (tid&1)<<4;   // A staging: row, col-offset (0/16)
  const int bsr = tid>>2, bsc = (tid&3)<<3;   // B staging: row, col-offset (0/8/16/24)
  const bool bok = (bn+bsr) < N;
  const float* Asrc = A + (size_t)asr*K + asc;
  const float* Bsrc = B + (size_t)(bn+bsr)*K + bsc;

  f32x4 acc[4][4] = {};

  for(int kt=0; kt<K; kt+=32){
    __syncthreads();
#pragma unroll
    for(int j=0;j<16;j+=2){
      float2 v = *(const float2*)(Asrc + kt + j);
      unsigned short hx=f2bf(v.x), hy=f2bf(v.y);
      unsigned short lx=f2bf(v.x - bf2f(hx)), ly=f2bf(v.y - bf2f(hy));
      *(unsigned*)&Ah[asr][asc+j] = ((unsigned)hy<<16)|hx;
      *(unsigned*)&Al[asr][asc+j] = ((unsigned)ly<<16)|lx;
    }
#pragma unroll
    for(int j=0;j<8;j+=2){
      float2 v = bok ? *(const float2*)(Bsrc + kt + j) : make_float2(0.f,0.f);
      unsigned short hx=f2bf(v.x), hy=f2bf(v.y);
      unsigned short lx=f2bf(v.x - bf2f(hx)), ly=f2bf(v.y - bf2f(hy));
      *(unsigned*)&Bh[bsr][bsc+j] = ((unsigned)hy<<16)|hx;
      *(unsigned*)&Bl[bsr][bsc+j] = ((unsigned)ly<<16)|lx;
    }
    __syncthreads();
    bf16x8 aH[4],aL[4],bH[4],bL[4];
#pragma unroll
    for(int f=0; f<4; ++f){
      const int ar = wr*64 + f*16 + l15;
      aH[f] = *(const bf16x8*)&Ah[ar][l4*8];
      aL[f] = *(const bf16x8*)&Al[ar][l4*8];
      const int br = wc*64 + f*16 + l15;
      bH[f] = *(const bf16x8*)&Bh[br][l4*8];
      bL[f] = *(const bf16x8*)&Bl[br][l4*8];
    }
#pragma unroll
    for(int i=0;i<4;++i)
#pragma unroll
      for(int j=0;j<4;++j){
        acc[i][j] = __builtin_amdgcn_mfma_f32_16x16x32_bf16(aH[i], bH[j], acc[i][j], 0,0,0);
        acc[i][j] = __builtin_amdgcn_mfma_f32_16x16x32_bf16(aH[i], bL[j], acc[i][j], 0,0,0);
        acc[i][j] = __builtin_amdgcn_mfma_f32_16x16x32_bf16(aL[i], bH[j], acc[i][j], 0,0,0);
      }
  }

#pragma unroll
  for(int i=0;i<4;++i){
#pragma unroll
    for(int j=0;j<4;++j){
      const int col = bn + wc*64 + j*16 + l15;
      if(col < N){
        const float bb = bias[col];
        const int row0 = wr*64 + i*16 + l4*4;
#pragma unroll
        for(int r=0;r<4;++r)
          C[(size_t)(row0+r)*N + col] = acc[i][j][r] + bb;
      }
    }
  }
}

// ---------------- persistent scan: R13 champion (UNCHANGED — control) ----------------
__global__ __launch_bounds__(256,1) void vae_scan(
    const float* __restrict__ enc_Whh, const float* __restrict__ dec_Whh,
    const float* __restrict__ pre_enc, const float* __restrict__ pre_dec,
    const float* __restrict__ h0in, const float* __restrict__ c0in,
    const float* __restrict__ ccond,
    const float* __restrict__ mean_W, const float* __restrict__ mean_b,
    const float* __restrict__ logvar_W, const float* __restrict__ logvar_b,
    const float* __restrict__ lc_W, const float* __restrict__ lc_b,
    ull* __restrict__ h_tag, ull* __restrict__ mlv_tag, ull* __restrict__ lat_tag,
    float* __restrict__ Hdec, float* __restrict__ out_mean, float* __restrict__ out_logvar)
{
  __shared__ float W_lds[16*1024];   // 64 KB, current phase
  __shared__ float h_lds[HID];
  __shared__ float lat_lds[LZD+CDD];
  __shared__ float sh_mlv[2*LZD];
  __shared__ float gbuf[16];
  __shared__ float redb[4];

  const int q = blockIdx.x, tid = threadIdx.x;
  const int g = tid>>4, l = tid&15;     // 16 groups x 16 lanes
  const int gate = g&3, ul = g>>2;
  const int u4 = 4*q;

  // ---- load encoder W_hh slice (conflict-free 16-lane-row layout) ----
  for(int r=0;r<16;++r){
    const float* src = enc_Whh + ((size_t)((r&3)*HID + u4 + (r>>2)))*HID;
    *(float4*)(&W_lds[r*1024 + tid*4]) = *(const float4*)(src + tid*4);
  }
  float creg = (tid<4) ? c0in[u4+tid] : 0.0f;

  // ---- encoder scan (2 barriers/step) ----
  for(int t=0; t<SEQ; ++t){
    float pv = 0.f;
    if(l==0) pv = pre_enc[(size_t)t*G4 + gate*HID + u4 + ul];  // issue-early
    if(t==0){
#pragma unroll
      for(int j=0;j<4;++j) h_lds[tid+j*256] = h0in[tid+j*256];
    }else{
      poll4(h_tag + (t&1)*HID, h_lds, tid, (unsigned)t);
    }
    __syncthreads();                                  // B1
    float a0=0,a1=0,a2=0,a3=0;
    {
      const float* wr = &W_lds[g*1024 + l*4];
      const float* hr = &h_lds[l*4];
#pragma unroll
      for(int kk=0; kk<16; ++kk){
        float4 wv = *(const float4*)(wr + kk*64);
        float4 hv = *(const float4*)(hr + kk*64);
        a0 = fmaf(wv.x, hv.x, a0);
        a1 = fmaf(wv.y, hv.y, a1);
        a2 = fmaf(wv.z, hv.z, a2);
        a3 = fmaf(wv.w, hv.w, a3);
      }
    }
    float s = (a0+a1)+(a2+a3);
    s += __shfl_xor(s,1); s += __shfl_xor(s,2); s += __shfl_xor(s,4); s += __shfl_xor(s,8);
    if(l==0) gbuf[g] = s + pv;
    __syncthreads();                                  // B2
    if(tid<4){
      float gi=gbuf[tid*4+0], gf=gbuf[tid*4+1], gg=gbuf[tid*4+2], go=gbuf[tid*4+3];
      float cn = sigm(gf)*creg + sigm(gi)*tanhf(gg);
      float hn = sigm(go)*tanhf(cn);
      creg = cn;
      pub_val(&h_tag[((t+1)&1)*HID + u4+tid], hn, (unsigned)(t+1));  // 1 coalesced 32B store
    }
  }

  // ---- mean/logvar: WG q computes row q of [mean;logvar]; h_enc = slot0 tag 256 ----
  {
    poll4(h_tag, h_lds, tid, (unsigned)SEQ);
    __syncthreads();
    const float* Wrow = (q < LZD) ? (mean_W + (size_t)q*HID)
                                  : (logvar_W + (size_t)(q-LZD)*HID);
    const float bias = (q < LZD) ? mean_b[q] : logvar_b[q-LZD];
    float4 hv = *(const float4*)(h_lds + tid*4);
    float4 wv = *(const float4*)(Wrow + tid*4);
    float p = hv.x*wv.x + hv.y*wv.y + hv.z*wv.z + hv.w*wv.w;
    p += __shfl_xor(p,1); p += __shfl_xor(p,2); p += __shfl_xor(p,4);
    p += __shfl_xor(p,8); p += __shfl_xor(p,16); p += __shfl_xor(p,32);
    if((tid&63)==0) redb[tid>>6] = p;
    __syncthreads();
    if(tid==0){
      float s = redb[0]+redb[1]+redb[2]+redb[3] + bias;
      pub_val(&mlv_tag[q], s, 1u);
      if(q < LZD) out_mean[q] = s; else out_logvar[q-LZD] = s;
    }
  }

  // ---- WG0: partitionable-threefry eps + latent ----
  if(q==0){
    sh_mlv[tid] = poll_val(&mlv_tag[tid], 1u);
    __syncthreads();
    if(tid < LZD){
      unsigned x0 = 0u, x1 = (unsigned)tid;          // counter (0, i)
      const unsigned ks[3] = {0u, 1u, 0x1BD11BDAu ^ 0u ^ 1u};  // key(1)
      x0 += ks[0]; x1 += ks[1];
      const int RA[4] = {13,15,26,6}, RB[4] = {17,29,16,24};
#pragma unroll
      for(int gg2=0; gg2<5; ++gg2){
        const int* R = (gg2&1) ? RB : RA;
#pragma unroll
        for(int qq=0;qq<4;++qq){
          x0 += x1;
          x1 = (x1 << R[qq]) | (x1 >> (32-R[qq]));
          x1 ^= x0;
        }
        x0 += ks[(gg2+1)%3];
        x1 += ks[(gg2+2)%3] + (unsigned)(gg2+1);
      }
      float e = eps_from_bits(x0 ^ x1);
      pub_val(&lat_tag[tid], fmaf(e, expf(0.5f*sh_mlv[LZD+tid]), sh_mlv[tid]), 1u);
    } else if(tid < LZD+CDD){
      pub_val(&lat_tag[tid], ccond[tid-LZD], 1u);
    }
  }

  // ---- switch to decoder weights; poll latent; dec h0 (tid<4 serial dot) ----
  for(int r=0;r<16;++r){
    const float* src = dec_Whh + ((size_t)((r&3)*HID + u4 + (r>>2)))*HID;
    *(float4*)(&W_lds[r*1024 + tid*4]) = *(const float4*)(src + tid*4);
  }
  if(tid < LZD+CDD) lat_lds[tid] = poll_val(&lat_tag[tid], 1u);
  __syncthreads();
  if(tid<4){
    const int j = u4 + tid;
    float s = lc_b[j];
    const float* wr = lc_W + (size_t)j*(LZD+CDD);
#pragma unroll 8
    for(int k=0;k<LZD+CDD;++k) s = fmaf(lat_lds[k], wr[k], s);
    creg = 0.0f;
    pub_val(&h_tag[j], s, DECTAG);   // slot 0, coalesced
  }

  // ---- decoder scan ----
  for(int t=0; t<SEQ; ++t){
    float pv = 0.f;
    if(l==0) pv = pre_dec[(size_t)t*G4 + gate*HID + u4 + ul];
    poll4(h_tag + (t&1)*HID, h_lds, tid, DECTAG + (unsigned)t);
    __syncthreads();                                  // B1
    float a0=0,a1=0,a2=0,a3=0;
    {
      const float* wr = &W_lds[g*1024 + l*4];
      const float* hr = &h_lds[l*4];
#pragma unroll
      for(int kk=0; kk<16; ++kk){
        float4 wv = *(const float4*)(wr + kk*64);
        float4 hv = *(const float4*)(hr + kk*64);
        a0 = fmaf(wv.x, hv.x, a0);
        a1 = fmaf(wv.y, hv.y, a1);
        a2 = fmaf(wv.z, hv.z, a2);
        a3 = fmaf(wv.w, hv.w, a3);
      }
    }
    float s = (a0+a1)+(a2+a3);
    s += __shfl_xor(s,1); s += __shfl_xor(s,2); s += __shfl_xor(s,4); s += __shfl_xor(s,8);
    if(l==0) gbuf[g] = s + pv;
    __syncthreads();                                  // B2
    if(tid<4){
      float gi=gbuf[tid*4+0], gf=gbuf[tid*4+1], gg=gbuf[tid*4+2], go=gbuf[tid*4+3];
      float cn = sigm(gf)*creg + sigm(gi)*tanhf(gg);
      float hn = sigm(go)*tanhf(cn);
      creg = cn;
      Hdec[(size_t)t*HID + u4 + tid] = hn;
      pub_val(&h_tag[((t+1)&1)*HID + u4+tid], hn, DECTAG + (unsigned)(t+1));
    }
  }
}

// ---------------- in-place log_softmax + first-index argmax ----------------
__global__ __launch_bounds__(256) void softmax_argmax(float* __restrict__ dist,
                                                      float* __restrict__ outTok)
{
  __shared__ float wm[4]; __shared__ int wi[4];
  __shared__ float s_max; __shared__ int s_idx; __shared__ float s_lz;
  const int t = blockIdx.x, tid = threadIdx.x;
  float* row = dist + (size_t)t*VOCAB;
  float m = -INFINITY; int idx = VOCAB;
  for(int i=tid; i<VOCAB; i+=256){
    float v = row[i];
    if(v > m){ m = v; idx = i; }
  }
  for(int d=1; d<64; d<<=1){
    float m2 = __shfl_xor(m, d); int i2 = __shfl_xor(idx, d);
    if(m2 > m || (m2 == m && i2 < idx)){ m = m2; idx = i2; }
  }
  if((tid&63)==0){ wm[tid>>6]=m; wi[tid>>6]=idx; }
  __syncthreads();
  if(tid==0){
    float mm = wm[0]; int ii = wi[0];
    for(int q=1;q<4;++q) if(wm[q]>mm || (wm[q]==mm && wi[q]<ii)){ mm=wm[q]; ii=wi[q]; }
    s_max = mm; s_idx = ii;
  }
  __syncthreads();
  const float M = s_max;
  float s = 0.f;
  for(int i=tid; i<VOCAB; i+=256) s += expf(row[i] - M);
  for(int d=1; d<64; d<<=1) s += __shfl_xor(s, d);
  if((tid&63)==0) wm[tid>>6] = s;
  __syncthreads();
  if(tid==0) s_lz = M + logf(wm[0]+wm[1]+wm[2]+wm[3]);
  __syncthreads();
  const float lz = s_lz;
  for(int i=tid; i<VOCAB; i+=256) row[i] -= lz;
  if(tid==0) outTok[t] = (float)s_idx;
}

// ---------------- launch ----------------
extern "C" void kernel_launch(void* const* d_in, const int* in_sizes, int n_in,
                              void* d_out, int out_size, void* d_ws, size_t ws_size,
                              hipStream_t stream)
{
  (void)in_sizes; (void)n_in; (void)out_size; (void)ws_size;
  const int*   tok      = (const int*)  d_in[0];
  const float* h0       = (const float*)d_in[1];
  const float* c0       = (const float*)d_in[2];
  const float* ccond    = (const float*)d_in[3];
  // d_in[4] = use_teacher_forcing (unused by reference body)
  const float* enc_emb  = (const float*)d_in[5];
  const float* enc_Wih  = (const float*)d_in[6];
  const float* enc_Whh  = (const float*)d_in[7];
  const float* enc_bih  = (const float*)d_in[8];
  const float* enc_bhh  = (const float*)d_in[9];
  const float* dec_emb  = (const float*)d_in[10];
  const float* dec_Wih  = (const float*)d_in[11];
  const float* dec_Whh  = (const float*)d_in[12];
  const float* dec_bih  = (const float*)d_in[13];
  const float* dec_bhh  = (const float*)d_in[14];
  const float* out_W    = (const float*)d_in[15];
  const float* out_b    = (const float*)d_in[16];
  const float* mean_W   = (const float*)d_in[17];
  const float* mean_b   = (const float*)d_in[18];
  const float* logvar_W = (const float*)d_in[19];
  const float* logvar_b = (const float*)d_in[20];
  const float* lc_W     = (const float*)d_in[21];
  const float* lc_b     = (const float*)d_in[22];

  float* ws      = (float*)d_ws;
  float* xenc    = ws;                       // 256*1024
  float* xdec    = xenc + SEQ*HID;           // 256*1024
  float* pre_enc = xdec + SEQ*HID;           // 256*4096
  float* pre_dec = pre_enc + (size_t)SEQ*G4; // 256*4096
  float* Hdec    = pre_dec + (size_t)SEQ*G4; // 256*1024
  ull*   tags    = (ull*)(Hdec + (size_t)SEQ*HID);  // 8B-aligned
  ull*   h_tag   = tags;                     // [2*1024]
  ull*   mlv_tag = h_tag + 2*HID;            // [256]
  ull*   lat_tag = mlv_tag + 2*LZD;          // [160]
  // total ~11.6 MB of ws

  float* out      = (float*)d_out;
  float* outTok   = out;                          // [256] tokens (as f32)
  float* dist     = out + SEQ;                    // [256,50257] log-softmax
  float* out_mean = dist + (size_t)SEQ*VOCAB;     // [128]
  float* out_lv   = out_mean + LZD;               // [128]

  hipLaunchKernelGGL(vae_embed, dim3(SEQ+1), dim3(256), 0, stream,
                     tok, enc_emb, dec_emb, xenc, xdec, tags);
  hipLaunchKernelGGL(gemm_pre, dim3(G4/64, SEQ/64, 2), dim3(256), 0, stream,
                     xenc, enc_Wih, enc_bih, enc_bhh,
                     xdec, dec_Wih, dec_bih, dec_bhh, pre_enc, pre_dec);
  hipLaunchKernelGGL(vae_scan, dim3(NWG), dim3(256), 0, stream,
                     enc_Whh, dec_Whh, pre_enc, pre_dec, h0, c0, ccond,
                     mean_W, mean_b, logvar_W, logvar_b, lc_W, lc_b,
                     h_tag, mlv_tag, lat_tag, Hdec, out_mean, out_lv);
  hipLaunchKernelGGL(gemm_logits_mfma, dim3((VOCAB+127)/128), dim3(512), 0, stream,
                     Hdec, out_W, out_b, dist, HID, VOCAB);
  hipLaunchKernelGGL(softmax_argmax, dim3(SEQ), dim3(256), 0, stream, dist, outTok);
}